// Round 9
// baseline (219.430 us; speedup 1.0000x reference)
//
#include <hip/hip_runtime.h>
#include <math.h>

#define NB 8
#define N_SRC 2048
#define N_DST 8192
#define C_SRC 128
#define C_SKIP 64
#define C_IN 192
#define C_H 128
#define N_ROWS (NB * N_DST)   /* 65536 */
#define BN_EPS 1e-5f
#define SLOPE 0.01f
#define GEMM_BLOCKS (N_ROWS / 64)   /* 1024 */

using short8 = __attribute__((ext_vector_type(8))) short;
using f32x4  = __attribute__((ext_vector_type(4))) float;

static __device__ __forceinline__ unsigned short f2bf(float f) {
    unsigned u = __builtin_bit_cast(unsigned, f);
    u = u + 0x7FFFu + ((u >> 16) & 1u);   // round-to-nearest-even
    return (unsigned short)(u >> 16);
}

// identical op order in both passes -> bitwise-identical d
static __device__ __forceinline__ float dist2(float px, float py, float pz,
                                              float4 s) {
    float dx = px - s.x, dy = py - s.y, dz = pz - s.z;
    return fmaf(dx, dx, fmaf(dy, dy, dz * dz));
}

// ---------------------------------------------------------------------------
// Prep: W1,W2 fp32 -> bf16 ([out][in] K-contiguous); pos -> float4 array.
// ---------------------------------------------------------------------------
__global__ __launch_bounds__(256) void k_prep(const float* __restrict__ W1,
                                              unsigned short* __restrict__ W1bf,
                                              const float* __restrict__ W2,
                                              unsigned short* __restrict__ W2bf,
                                              const float* __restrict__ pos,
                                              float4* __restrict__ pos4) {
    int gid = blockIdx.x * 256 + threadIdx.x;
    int stride = gridDim.x * 256;
    for (int i = gid; i < C_H * C_IN; i += stride) W1bf[i] = f2bf(W1[i]);
    for (int i = gid; i < C_H * C_H; i += stride)  W2bf[i] = f2bf(W2[i]);
    for (int p = gid; p < NB * N_SRC; p += stride) {
        pos4[p] = make_float4(pos[p * 3 + 0], pos[p * 3 + 1], pos[p * 3 + 2], 0.f);
    }
}

// ---------------------------------------------------------------------------
// Fused KNN + GEMM1. Block = 64 dst rows, 4 waves, wave scans 512-pt segment.
// Pass 1: distance-only top-3 via min/med3 (no cmp/cndmask chain), LDS
//         uniform-address broadcast reads.
// Merge:  distance-triples across 4 waves -> (e0,e1,e2) + weights.
// Pass 2: rescan, recover indices by equality-class vs (e0,e1,e2);
//         descending j keeps lowest-index ties.
// Then:   gather+interp A-tile bf16; MFMA; lrelu; h1 -> out; BN1 partials.
// ---------------------------------------------------------------------------
__global__ __launch_bounds__(256) void k_fused1(const float4* __restrict__ pos4,
                                                const float* __restrict__ pos_skip,
                                                const float* __restrict__ x,
                                                const float* __restrict__ x_skip,
                                                const unsigned short* __restrict__ Wbf,
                                                const float* __restrict__ bias,
                                                float* __restrict__ out,
                                                float* __restrict__ ps,
                                                float* __restrict__ pq) {
    __shared__ __align__(16) char Lds[38400];
    // region1 [0,32768): sp float4[2048]  (scan)  OR  Ash us[64][200] (gemm)
    float4* sp = (float4*)Lds;
    unsigned short (*Ash)[200] = (unsigned short(*)[200])Lds;
    // region2 [32768,36864): cd f[4*64*3] + eD f[64*3] (scan)
    //                        OR sS f[4*128] + sQ f[4*128] (epilogue)
    float* cd = (float*)(Lds + 32768);
    float* eD = (float*)(Lds + 32768 + 3072);
    float* sS = (float*)(Lds + 32768);
    float* sQ = (float*)(Lds + 32768 + 2048);
    // region3 [36864,38400): midx i[64*3], mw f[64*3]
    int*   midx = (int*)(Lds + 36864);
    float* mw   = (float*)(Lds + 36864 + 768);

    int tid = threadIdx.x;
    int l = tid & 63, w = tid >> 6;
    int cloud = blockIdx.x >> 7;
    int r0 = blockIdx.x * 64;

    // ---- stage src points into LDS (coalesced) ----
    for (int i = tid; i < N_SRC; i += 256) sp[i] = pos4[(cloud << 11) + i];

    int dst = r0 + l;
    float px = pos_skip[dst * 3 + 0];
    float py = pos_skip[dst * 3 + 1];
    float pz = pos_skip[dst * 3 + 2];
    __syncthreads();

    // ---------------- Pass 1: distance-only top-3 ----------------
    const float4* seg = sp + (w << 9);
    float d0 = 3.4e38f, d1 = 3.4e38f, d2 = 3.4e38f;
    for (int c = 0; c < 16; ++c) {
#pragma unroll
        for (int k = 0; k < 32; ++k) {
            float d = dist2(px, py, pz, seg[c * 32 + k]);  // uniform -> broadcast
            float nd2 = __builtin_amdgcn_fmed3f(d, d1, d2);
            float nd1 = __builtin_amdgcn_fmed3f(d, d0, d1);
            d0 = fminf(d0, d);
            d1 = nd1; d2 = nd2;
        }
    }
    cd[(w * 64 + l) * 3 + 0] = d0;
    cd[(w * 64 + l) * 3 + 1] = d1;
    cd[(w * 64 + l) * 3 + 2] = d2;
    __syncthreads();

    // ---------------- merge distance triples (no indices) ----------------
    if (tid < 64) {
        float e0 = 3.4e38f, e1 = 3.4e38f, e2 = 3.4e38f;
#pragma unroll
        for (int s = 0; s < 4; ++s) {
#pragma unroll
            for (int t = 0; t < 3; ++t) {
                float d = cd[(s * 64 + tid) * 3 + t];
                float ne2 = __builtin_amdgcn_fmed3f(d, e1, e2);
                float ne1 = __builtin_amdgcn_fmed3f(d, e0, e1);
                e0 = fminf(e0, d);
                e1 = ne1; e2 = ne2;
            }
        }
        float w0 = 1.f / fmaxf(e0, 1e-16f);
        float w1 = 1.f / fmaxf(e1, 1e-16f);
        float w2 = 1.f / fmaxf(e2, 1e-16f);
        float inv = 1.f / (w0 + w1 + w2);
        mw[tid * 3 + 0] = w0 * inv;
        mw[tid * 3 + 1] = w1 * inv;
        mw[tid * 3 + 2] = w2 * inv;
        eD[tid * 3 + 0] = e0; eD[tid * 3 + 1] = e1; eD[tid * 3 + 2] = e2;
        midx[tid * 3 + 0] = 0; midx[tid * 3 + 1] = 0; midx[tid * 3 + 2] = 0;
    }
    __syncthreads();

    // ---------------- Pass 2: index recovery (descending j) ----------------
    float e0r = eD[l * 3 + 0];
    float e1r = eD[l * 3 + 1];
    float e2r = eD[l * 3 + 2];
    for (int c = 15; c >= 0; --c) {
#pragma unroll
        for (int k = 31; k >= 0; --k) {
            float d = dist2(px, py, pz, seg[c * 32 + k]);
            if (d <= e2r) {                       // wave-taken ~9%
                int j = (w << 9) + c * 32 + k;
                int slot = d <= e0r ? 0 : (d <= e1r ? 1 : 2);
                midx[l * 3 + slot] = j;
            }
        }
    }
    __syncthreads();

    // ---------------- gather + interp -> bf16 A tile ----------------
    const float* xb = x + (size_t)cloud * N_SRC * C_SRC;
    for (int rr = w * 16; rr < w * 16 + 16; ++rr) {
        int j0 = midx[rr * 3 + 0], j1 = midx[rr * 3 + 1], j2 = midx[rr * 3 + 2];
        float w0 = mw[rr * 3 + 0], w1 = mw[rr * 3 + 1], w2 = mw[rr * 3 + 2];
        const float2* x0v = (const float2*)(xb + (size_t)j0 * C_SRC);
        const float2* x1v = (const float2*)(xb + (size_t)j1 * C_SRC);
        const float2* x2v = (const float2*)(xb + (size_t)j2 * C_SRC);
        float2 a = x0v[l], b = x1v[l], c = x2v[l];
        float v0 = w0 * a.x + w1 * b.x + w2 * c.x;
        float v1 = w0 * a.y + w1 * b.y + w2 * c.y;
        ((unsigned*)&Ash[rr][0])[l] = (unsigned)f2bf(v0) | ((unsigned)f2bf(v1) << 16);
        Ash[rr][128 + l] = f2bf(x_skip[(size_t)(r0 + rr) * C_SKIP + l]);
    }
    // waves read only their own 16-row slab -> no barrier needed

    // ---------------- MFMA ----------------
    int cl = l & 15, kh = l >> 4;
    f32x4 acc[8];
#pragma unroll
    for (int n = 0; n < 8; ++n) {
        float bv = bias[n * 16 + cl];
        acc[n][0] = bv; acc[n][1] = bv; acc[n][2] = bv; acc[n][3] = bv;
    }
    const unsigned short* wb = Wbf + (size_t)cl * C_IN + kh * 8;
    for (int kt = 0; kt < 6; ++kt) {
        short8 af = *(const short8*)&Ash[w * 16 + cl][kt * 32 + kh * 8];
#pragma unroll
        for (int n = 0; n < 8; ++n) {
            short8 bf = *(const short8*)(wb + (size_t)n * 16 * C_IN + kt * 32);
            acc[n] = __builtin_amdgcn_mfma_f32_16x16x32_bf16(af, bf, acc[n], 0, 0, 0);
        }
    }

    // ---------------- epilogue: lrelu + store fp32 + BN1 partials ----------
    float pss[8], pqs[8];
#pragma unroll
    for (int n = 0; n < 8; ++n) {
        float s = 0.f, q = 0.f;
        int col = n * 16 + cl;
#pragma unroll
        for (int j = 0; j < 4; ++j) {
            int row = r0 + w * 16 + kh * 4 + j;
            float z = acc[n][j];
            z = z > 0.f ? z : SLOPE * z;
            out[(size_t)row * C_H + col] = z;
            s += z; q += z * z;
        }
        s += __shfl_xor(s, 16); s += __shfl_xor(s, 32);
        q += __shfl_xor(q, 16); q += __shfl_xor(q, 32);
        pss[n] = s; pqs[n] = q;
    }
    __syncthreads();   // region2 reuse: all pass-2/merge readers are done
    if (l < 16) {
#pragma unroll
        for (int n = 0; n < 8; ++n) {
            sS[w * 128 + n * 16 + l] = pss[n];
            sQ[w * 128 + n * 16 + l] = pqs[n];
        }
    }
    __syncthreads();
    if (tid < 128) {
        float s = sS[0 * 128 + tid] + sS[1 * 128 + tid] +
                  sS[2 * 128 + tid] + sS[3 * 128 + tid];
        float q = sQ[0 * 128 + tid] + sQ[1 * 128 + tid] +
                  sQ[2 * 128 + tid] + sQ[3 * 128 + tid];
        ps[blockIdx.x * C_H + tid] = s;
        pq[blockIdx.x * C_H + tid] = q;
    }
}

// ---------------------------------------------------------------------------
// Per-channel reduce of block partials -> BN affine
// ---------------------------------------------------------------------------
__global__ __launch_bounds__(256) void k_reduce(const float* __restrict__ ps,
                                                const float* __restrict__ pq,
                                                const float* __restrict__ g,
                                                const float* __restrict__ be,
                                                float* __restrict__ a_out,
                                                float* __restrict__ c_out) {
    int col = blockIdx.x;
    float s = 0.f, q = 0.f;
    for (int b = threadIdx.x; b < GEMM_BLOCKS; b += 256) {
        s += ps[b * C_H + col];
        q += pq[b * C_H + col];
    }
    for (int off = 32; off; off >>= 1) {
        s += __shfl_down(s, off);
        q += __shfl_down(q, off);
    }
    __shared__ float rs[4], rq[4];
    if ((threadIdx.x & 63) == 0) { rs[threadIdx.x >> 6] = s; rq[threadIdx.x >> 6] = q; }
    __syncthreads();
    if (threadIdx.x == 0) {
        s = rs[0] + rs[1] + rs[2] + rs[3];
        q = rq[0] + rq[1] + rq[2] + rq[3];
        float mean = s / (float)N_ROWS;
        float var  = q / (float)N_ROWS - mean * mean;
        float a = g[col] * rsqrtf(var + BN_EPS);
        a_out[col] = a;
        c_out[col] = be[col] - mean * a;
    }
}

// ---------------------------------------------------------------------------
// GEMM2a: stats-only pass. Stage Ash = bf16(a1*h1 + c1) (BN1 applied here);
// z2 = Ash@W2bf^T + b2; lrelu; BN2 partials. No store.
// ---------------------------------------------------------------------------
__global__ __launch_bounds__(256) void k_g2a(const float* __restrict__ h,
                                             const unsigned short* __restrict__ Wbf,
                                             const float* __restrict__ b2,
                                             const float* __restrict__ a1,
                                             const float* __restrict__ c1,
                                             float* __restrict__ ps,
                                             float* __restrict__ pq) {
    __shared__ __align__(16) unsigned short Ash[64][136];
    __shared__ float sS[4][128];
    __shared__ float sQ[4][128];

    int r0 = blockIdx.x * 64;
    int tid = threadIdx.x;
    int l = tid & 63, w = tid >> 6;

    const float* src = h + (size_t)r0 * C_H;
    for (int i = tid * 4; i < 64 * C_H; i += 1024) {
        float4 v = *(const float4*)&src[i];
        int r = i >> 7, c = i & 127;
        float4 av = *(const float4*)&a1[c];
        float4 cv = *(const float4*)&c1[c];
        unsigned lo = (unsigned)f2bf(fmaf(av.x, v.x, cv.x)) |
                      ((unsigned)f2bf(fmaf(av.y, v.y, cv.y)) << 16);
        unsigned hi = (unsigned)f2bf(fmaf(av.z, v.z, cv.z)) |
                      ((unsigned)f2bf(fmaf(av.w, v.w, cv.w)) << 16);
        *(uint2*)&Ash[r][c] = make_uint2(lo, hi);
    }
    __syncthreads();

    int cl = l & 15, kh = l >> 4;
    f32x4 acc[8];
#pragma unroll
    for (int n = 0; n < 8; ++n) {
        float bv = b2[n * 16 + cl];
        acc[n][0] = bv; acc[n][1] = bv; acc[n][2] = bv; acc[n][3] = bv;
    }
    const unsigned short* wb = Wbf + (size_t)cl * C_H + kh * 8;
    for (int kt = 0; kt < 4; ++kt) {
        short8 af = *(const short8*)&Ash[w * 16 + cl][kt * 32 + kh * 8];
#pragma unroll
        for (int n = 0; n < 8; ++n) {
            short8 bf = *(const short8*)(wb + (size_t)n * 16 * C_H + kt * 32);
            acc[n] = __builtin_amdgcn_mfma_f32_16x16x32_bf16(af, bf, acc[n], 0, 0, 0);
        }
    }

    float pss[8], pqs[8];
#pragma unroll
    for (int n = 0; n < 8; ++n) {
        float s = 0.f, q = 0.f;
#pragma unroll
        for (int j = 0; j < 4; ++j) {
            float z = acc[n][j];
            z = z > 0.f ? z : SLOPE * z;
            s += z; q += z * z;
        }
        s += __shfl_xor(s, 16); s += __shfl_xor(s, 32);
        q += __shfl_xor(q, 16); q += __shfl_xor(q, 32);
        pss[n] = s; pqs[n] = q;
    }
    if (l < 16) {
#pragma unroll
        for (int n = 0; n < 8; ++n) {
            sS[w][n * 16 + l] = pss[n];
            sQ[w][n * 16 + l] = pqs[n];
        }
    }
    __syncthreads();
    if (tid < 128) {
        float s = sS[0][tid] + sS[1][tid] + sS[2][tid] + sS[3][tid];
        float q = sQ[0][tid] + sQ[1][tid] + sQ[2][tid] + sQ[3][tid];
        ps[blockIdx.x * C_H + tid] = s;
        pq[blockIdx.x * C_H + tid] = q;
    }
}

// ---------------------------------------------------------------------------
// GEMM2b: recompute z2 (same staging), lrelu + BN2 affine, write d_out in
// place (block reads only its own 64 rows -> race-free). Copies pos/batch.
// ---------------------------------------------------------------------------
__global__ __launch_bounds__(256) void k_g2b(float* __restrict__ h,
                                             const unsigned short* __restrict__ Wbf,
                                             const float* __restrict__ b2,
                                             const float* __restrict__ a1,
                                             const float* __restrict__ c1,
                                             const float* __restrict__ a2,
                                             const float* __restrict__ c2,
                                             const float* __restrict__ pos_skip,
                                             const int* __restrict__ batch_skip,
                                             float* __restrict__ out_pos,
                                             float* __restrict__ out_batch) {
    __shared__ __align__(16) unsigned short Ash[64][136];

    int r0 = blockIdx.x * 64;
    int tid = threadIdx.x;
    int l = tid & 63, w = tid >> 6;

    if (tid < 192) out_pos[(size_t)r0 * 3 + tid] = pos_skip[(size_t)r0 * 3 + tid];
    if (tid < 64)  out_batch[r0 + tid] = (float)batch_skip[r0 + tid];

    const float* src = h + (size_t)r0 * C_H;
    for (int i = tid * 4; i < 64 * C_H; i += 1024) {
        float4 v = *(const float4*)&src[i];
        int r = i >> 7, c = i & 127;
        float4 av = *(const float4*)&a1[c];
        float4 cv = *(const float4*)&c1[c];
        unsigned lo = (unsigned)f2bf(fmaf(av.x, v.x, cv.x)) |
                      ((unsigned)f2bf(fmaf(av.y, v.y, cv.y)) << 16);
        unsigned hi = (unsigned)f2bf(fmaf(av.z, v.z, cv.z)) |
                      ((unsigned)f2bf(fmaf(av.w, v.w, cv.w)) << 16);
        *(uint2*)&Ash[r][c] = make_uint2(lo, hi);
    }
    __syncthreads();

    int cl = l & 15, kh = l >> 4;
    f32x4 acc[8];
#pragma unroll
    for (int n = 0; n < 8; ++n) {
        float bv = b2[n * 16 + cl];
        acc[n][0] = bv; acc[n][1] = bv; acc[n][2] = bv; acc[n][3] = bv;
    }
    const unsigned short* wb = Wbf + (size_t)cl * C_H + kh * 8;
    for (int kt = 0; kt < 4; ++kt) {
        short8 af = *(const short8*)&Ash[w * 16 + cl][kt * 32 + kh * 8];
#pragma unroll
        for (int n = 0; n < 8; ++n) {
            short8 bf = *(const short8*)(wb + (size_t)n * 16 * C_H + kt * 32);
            acc[n] = __builtin_amdgcn_mfma_f32_16x16x32_bf16(af, bf, acc[n], 0, 0, 0);
        }
    }

#pragma unroll
    for (int n = 0; n < 8; ++n) {
        int col = n * 16 + cl;
        float av = a2[col], cv = c2[col];
#pragma unroll
        for (int j = 0; j < 4; ++j) {
            int row = r0 + w * 16 + kh * 4 + j;
            float z = acc[n][j];
            z = z > 0.f ? z : SLOPE * z;
            h[(size_t)row * C_H + col] = av * z + cv;
        }
    }
}

// ---------------------------------------------------------------------------
extern "C" void kernel_launch(void* const* d_in, const int* in_sizes, int n_in,
                              void* d_out, int out_size, void* d_ws, size_t ws_size,
                              hipStream_t stream) {
    const float* x          = (const float*)d_in[0];
    const float* pos        = (const float*)d_in[1];
    const float* x_skip     = (const float*)d_in[3];
    const float* pos_skip   = (const float*)d_in[4];
    const int*   batch_skip = (const int*)d_in[5];
    const float* W1  = (const float*)d_in[6];
    const float* b1  = (const float*)d_in[7];
    const float* g1  = (const float*)d_in[8];
    const float* be1 = (const float*)d_in[9];
    const float* W2  = (const float*)d_in[10];
    const float* b2  = (const float*)d_in[11];
    const float* g2  = (const float*)d_in[12];
    const float* be2 = (const float*)d_in[13];

    float* out_h     = (float*)d_out;
    float* out_pos   = out_h + (size_t)N_ROWS * C_H;
    float* out_batch = out_pos + (size_t)N_ROWS * 3;

    float* wsf = (float*)d_ws;
    float4* pos4         = (float4*)wsf;                         // 65536 floats
    unsigned short* W1bf = (unsigned short*)(wsf + 65536);       // 24576 us
    unsigned short* W2bf = (unsigned short*)(wsf + 77824);       // 16384 us
    float* p1s = wsf + 86016;                                    // 131072
    float* p1q = p1s + 131072;
    float* p2s = p1q + 131072;
    float* p2q = p2s + 131072;
    float* a1g = p2q + 131072;
    float* c1g = a1g + 128;
    float* a2g = c1g + 128;
    float* c2g = a2g + 128;

    k_prep<<<64, 256, 0, stream>>>(W1, W1bf, W2, W2bf, pos, pos4);
    k_fused1<<<GEMM_BLOCKS, 256, 0, stream>>>(pos4, pos_skip, x, x_skip, W1bf, b1,
                                              out_h, p1s, p1q);
    k_reduce<<<C_H, 256, 0, stream>>>(p1s, p1q, g1, be1, a1g, c1g);
    k_g2a<<<GEMM_BLOCKS, 256, 0, stream>>>(out_h, W2bf, b2, a1g, c1g, p2s, p2q);
    k_reduce<<<C_H, 256, 0, stream>>>(p2s, p2q, g2, be2, a2g, c2g);
    k_g2b<<<GEMM_BLOCKS, 256, 0, stream>>>(out_h, W2bf, b2, a1g, c1g, a2g, c2g,
                                           pos_skip, batch_skip, out_pos, out_batch);
}

// Round 10
// 162.494 us; speedup vs baseline: 1.3504x; 1.3504x over previous
//
#include <hip/hip_runtime.h>
#include <math.h>

#define NB 8
#define N_SRC 2048
#define N_DST 8192
#define C_SRC 128
#define C_SKIP 64
#define C_IN 192
#define C_H 128
#define N_ROWS (NB * N_DST)   /* 65536 */
#define BN_EPS 1e-5f
#define SLOPE 0.01f
#define GEMM_BLOCKS (N_ROWS / 64)   /* 1024 */

using short8 = __attribute__((ext_vector_type(8))) short;
using f32x4  = __attribute__((ext_vector_type(4))) float;

static __device__ __forceinline__ unsigned short f2bf(float f) {
    unsigned u = __builtin_bit_cast(unsigned, f);
    u = u + 0x7FFFu + ((u >> 16) & 1u);   // round-to-nearest-even
    return (unsigned short)(u >> 16);
}

// ---------------------------------------------------------------------------
// Prep: W1,W2 fp32 -> bf16 ([out][in] K-contiguous); pos -> float4 array.
// ---------------------------------------------------------------------------
__global__ __launch_bounds__(256) void k_prep(const float* __restrict__ W1,
                                              unsigned short* __restrict__ W1bf,
                                              const float* __restrict__ W2,
                                              unsigned short* __restrict__ W2bf,
                                              const float* __restrict__ pos,
                                              float4* __restrict__ pos4) {
    int gid = blockIdx.x * 256 + threadIdx.x;
    int stride = gridDim.x * 256;
    for (int i = gid; i < C_H * C_IN; i += stride) W1bf[i] = f2bf(W1[i]);
    for (int i = gid; i < C_H * C_H; i += stride)  W2bf[i] = f2bf(W2[i]);
    for (int p = gid; p < NB * N_SRC; p += stride) {
        pos4[p] = make_float4(pos[p * 3 + 0], pos[p * 3 + 1], pos[p * 3 + 2], 0.f);
    }
}

// ---------------------------------------------------------------------------
// Fused KNN + GEMM1. Block = 64 dst rows, 4 waves.
// Phase A: top-3 scan over per-wave 512-pt segment. Segment prefetched into
//          VGPRs (8 coalesced float4/lane), points broadcast via v_readlane
//          (VALU pipe; LDS pipe untouched). BRANCHLESS insert: distances via
//          fmin + 2x fmed3 (3 one-op dep chains), indices via 3 cmp + 5
//          cndmask. ~20 VALU-instr per wave-iteration (64 pairs).
// Phase B: merge 12 candidates; gather+interp A-tile bf16; MFMA; lrelu;
//          h1 fp32 -> out; BN1 partial sums.
// ---------------------------------------------------------------------------
__global__ __launch_bounds__(256) void k_fused1(const float4* __restrict__ pos4,
                                                const float* __restrict__ pos_skip,
                                                const float* __restrict__ x,
                                                const float* __restrict__ x_skip,
                                                const unsigned short* __restrict__ Wbf,
                                                const float* __restrict__ bias,
                                                float* __restrict__ out,
                                                float* __restrict__ ps,
                                                float* __restrict__ pq) {
    __shared__ __align__(16) unsigned short Ash[64][200];   // 25600 B (cd/ci overlay)
    __shared__ float sS[4][128];
    __shared__ float sQ[4][128];
    __shared__ int   midx[64][3];
    __shared__ float mw[64][3];

    float* cd = (float*)&Ash[0][0];                  // [4][64][3] floats
    int*   ci = (int*)((char*)&Ash[0][0] + 3072);    // [4][64][3] ints

    int tid = threadIdx.x;
    int l = tid & 63, w = tid >> 6;
    int cloud = blockIdx.x >> 7;
    int r0 = blockIdx.x * 64;

    // ---------------- Phase A: KNN scan ----------------
    int dst = r0 + l;
    float px = pos_skip[dst * 3 + 0];
    float py = pos_skip[dst * 3 + 1];
    float pz = pos_skip[dst * 3 + 2];

    // prefetch the wave's 512-point segment into VGPRs (coalesced)
    const float4* __restrict__ pw = pos4 + (cloud << 11) + (w << 9);
    float4 C[8];
#pragma unroll
    for (int c = 0; c < 8; ++c) C[c] = pw[c * 64 + l];

    float rr0 = 3.4e38f, rr1 = 3.4e38f, rr2 = 3.4e38f;
    int   ii0 = 0, ii1 = 0, ii2 = 0;
#pragma unroll
    for (int c = 0; c < 8; ++c) {
        int jb = (w << 9) + c * 64;
        int vx = __float_as_int(C[c].x);
        int vy = __float_as_int(C[c].y);
        int vz = __float_as_int(C[c].z);
#pragma unroll 16
        for (int k = 0; k < 64; ++k) {
            float sx = __int_as_float(__builtin_amdgcn_readlane(vx, k));
            float sy = __int_as_float(__builtin_amdgcn_readlane(vy, k));
            float sz = __int_as_float(__builtin_amdgcn_readlane(vz, k));
            float dx = px - sx, dy = py - sy, dz = pz - sz;
            float d = fmaf(dx, dx, fmaf(dy, dy, dz * dz));
            int jj = jb + k;
            bool c0 = d < rr0, c1 = d < rr1, c2 = d < rr2;
            ii2 = c1 ? ii1 : (c2 ? jj : ii2);
            ii1 = c0 ? ii0 : (c1 ? jj : ii1);
            ii0 = c0 ? jj : ii0;
            rr2 = __builtin_amdgcn_fmed3f(d, rr1, rr2);   // uses old rr1
            rr1 = __builtin_amdgcn_fmed3f(d, rr0, rr1);   // uses old rr0
            rr0 = fminf(rr0, d);
        }
    }
    cd[(w * 64 + l) * 3 + 0] = rr0; ci[(w * 64 + l) * 3 + 0] = ii0;
    cd[(w * 64 + l) * 3 + 1] = rr1; ci[(w * 64 + l) * 3 + 1] = ii1;
    cd[(w * 64 + l) * 3 + 2] = rr2; ci[(w * 64 + l) * 3 + 2] = ii2;
    __syncthreads();

    // ---------------- merge 12 candidates per dst ----------------
    if (tid < 64) {
        float e0 = 3.4e38f, e1 = 3.4e38f, e2 = 3.4e38f;
        int   m0 = 0, m1 = 0, m2 = 0;
#pragma unroll
        for (int s = 0; s < 4; ++s) {
#pragma unroll
            for (int t = 0; t < 3; ++t) {
                float d = cd[(s * 64 + tid) * 3 + t];
                int  jj = ci[(s * 64 + tid) * 3 + t];
                bool c0 = d < e0, c1 = d < e1, c2 = d < e2;
                m2 = c1 ? m1 : (c2 ? jj : m2);
                m1 = c0 ? m0 : (c1 ? jj : m1);
                m0 = c0 ? jj : m0;
                e2 = __builtin_amdgcn_fmed3f(d, e1, e2);
                e1 = __builtin_amdgcn_fmed3f(d, e0, e1);
                e0 = fminf(e0, d);
            }
        }
        float w0 = 1.f / fmaxf(e0, 1e-16f);
        float w1 = 1.f / fmaxf(e1, 1e-16f);
        float w2 = 1.f / fmaxf(e2, 1e-16f);
        float inv = 1.f / (w0 + w1 + w2);
        midx[tid][0] = m0; midx[tid][1] = m1; midx[tid][2] = m2;
        mw[tid][0] = w0 * inv; mw[tid][1] = w1 * inv; mw[tid][2] = w2 * inv;
    }
    __syncthreads();

    // ---------------- Phase B: gather + interp -> bf16 A tile ----------------
    const float* xb = x + (size_t)cloud * N_SRC * C_SRC;
    for (int rr = w * 16; rr < w * 16 + 16; ++rr) {
        int j0 = midx[rr][0], j1 = midx[rr][1], j2 = midx[rr][2];
        float w0 = mw[rr][0], w1 = mw[rr][1], w2 = mw[rr][2];
        const float2* x0v = (const float2*)(xb + (size_t)j0 * C_SRC);
        const float2* x1v = (const float2*)(xb + (size_t)j1 * C_SRC);
        const float2* x2v = (const float2*)(xb + (size_t)j2 * C_SRC);
        float2 a = x0v[l], b = x1v[l], c = x2v[l];
        float v0 = w0 * a.x + w1 * b.x + w2 * c.x;
        float v1 = w0 * a.y + w1 * b.y + w2 * c.y;
        ((unsigned*)&Ash[rr][0])[l] = (unsigned)f2bf(v0) | ((unsigned)f2bf(v1) << 16);
        Ash[rr][128 + l] = f2bf(x_skip[(size_t)(r0 + rr) * C_SKIP + l]);
    }
    // waves read only their own 16-row slab -> no barrier needed

    // ---------------- MFMA ----------------
    int cl = l & 15, kh = l >> 4;
    f32x4 acc[8];
#pragma unroll
    for (int n = 0; n < 8; ++n) {
        float bv = bias[n * 16 + cl];
        acc[n][0] = bv; acc[n][1] = bv; acc[n][2] = bv; acc[n][3] = bv;
    }
    const unsigned short* wb = Wbf + (size_t)cl * C_IN + kh * 8;
    for (int kt = 0; kt < 6; ++kt) {
        short8 af = *(const short8*)&Ash[w * 16 + cl][kt * 32 + kh * 8];
#pragma unroll
        for (int n = 0; n < 8; ++n) {
            short8 bf = *(const short8*)(wb + (size_t)n * 16 * C_IN + kt * 32);
            acc[n] = __builtin_amdgcn_mfma_f32_16x16x32_bf16(af, bf, acc[n], 0, 0, 0);
        }
    }

    // ---------------- epilogue: lrelu + store fp32 + BN1 partials ----------------
    float pss[8], pqs[8];
#pragma unroll
    for (int n = 0; n < 8; ++n) {
        float s = 0.f, q = 0.f;
        int col = n * 16 + cl;
#pragma unroll
        for (int j = 0; j < 4; ++j) {
            int row = r0 + w * 16 + kh * 4 + j;
            float z = acc[n][j];
            z = z > 0.f ? z : SLOPE * z;
            out[(size_t)row * C_H + col] = z;
            s += z; q += z * z;
        }
        s += __shfl_xor(s, 16); s += __shfl_xor(s, 32);
        q += __shfl_xor(q, 16); q += __shfl_xor(q, 32);
        pss[n] = s; pqs[n] = q;
    }
    if (l < 16) {
#pragma unroll
        for (int n = 0; n < 8; ++n) {
            sS[w][n * 16 + l] = pss[n];
            sQ[w][n * 16 + l] = pqs[n];
        }
    }
    __syncthreads();
    if (tid < 128) {
        float s = sS[0][tid] + sS[1][tid] + sS[2][tid] + sS[3][tid];
        float q = sQ[0][tid] + sQ[1][tid] + sQ[2][tid] + sQ[3][tid];
        ps[blockIdx.x * C_H + tid] = s;
        pq[blockIdx.x * C_H + tid] = q;
    }
}

// ---------------------------------------------------------------------------
// Per-channel reduce of block partials -> BN affine
// ---------------------------------------------------------------------------
__global__ __launch_bounds__(256) void k_reduce(const float* __restrict__ ps,
                                                const float* __restrict__ pq,
                                                const float* __restrict__ g,
                                                const float* __restrict__ be,
                                                float* __restrict__ a_out,
                                                float* __restrict__ c_out) {
    int col = blockIdx.x;
    float s = 0.f, q = 0.f;
    for (int b = threadIdx.x; b < GEMM_BLOCKS; b += 256) {
        s += ps[b * C_H + col];
        q += pq[b * C_H + col];
    }
    for (int off = 32; off; off >>= 1) {
        s += __shfl_down(s, off);
        q += __shfl_down(q, off);
    }
    __shared__ float rs[4], rq[4];
    if ((threadIdx.x & 63) == 0) { rs[threadIdx.x >> 6] = s; rq[threadIdx.x >> 6] = q; }
    __syncthreads();
    if (threadIdx.x == 0) {
        s = rs[0] + rs[1] + rs[2] + rs[3];
        q = rq[0] + rq[1] + rq[2] + rq[3];
        float mean = s / (float)N_ROWS;
        float var  = q / (float)N_ROWS - mean * mean;
        float a = g[col] * rsqrtf(var + BN_EPS);
        a_out[col] = a;
        c_out[col] = be[col] - mean * a;
    }
}

// ---------------------------------------------------------------------------
// GEMM2a: stats-only pass. Stage Ash = bf16(a1*h1 + c1) (BN1 applied here);
// z2 = Ash@W2bf^T + b2; lrelu; BN2 partials. No store.
// ---------------------------------------------------------------------------
__global__ __launch_bounds__(256) void k_g2a(const float* __restrict__ h,
                                             const unsigned short* __restrict__ Wbf,
                                             const float* __restrict__ b2,
                                             const float* __restrict__ a1,
                                             const float* __restrict__ c1,
                                             float* __restrict__ ps,
                                             float* __restrict__ pq) {
    __shared__ __align__(16) unsigned short Ash[64][136];
    __shared__ float sS[4][128];
    __shared__ float sQ[4][128];

    int r0 = blockIdx.x * 64;
    int tid = threadIdx.x;
    int l = tid & 63, w = tid >> 6;

    const float* src = h + (size_t)r0 * C_H;
    for (int i = tid * 4; i < 64 * C_H; i += 1024) {
        float4 v = *(const float4*)&src[i];
        int r = i >> 7, c = i & 127;
        float4 av = *(const float4*)&a1[c];
        float4 cv = *(const float4*)&c1[c];
        unsigned lo = (unsigned)f2bf(fmaf(av.x, v.x, cv.x)) |
                      ((unsigned)f2bf(fmaf(av.y, v.y, cv.y)) << 16);
        unsigned hi = (unsigned)f2bf(fmaf(av.z, v.z, cv.z)) |
                      ((unsigned)f2bf(fmaf(av.w, v.w, cv.w)) << 16);
        *(uint2*)&Ash[r][c] = make_uint2(lo, hi);
    }
    __syncthreads();

    int cl = l & 15, kh = l >> 4;
    f32x4 acc[8];
#pragma unroll
    for (int n = 0; n < 8; ++n) {
        float bv = b2[n * 16 + cl];
        acc[n][0] = bv; acc[n][1] = bv; acc[n][2] = bv; acc[n][3] = bv;
    }
    const unsigned short* wb = Wbf + (size_t)cl * C_H + kh * 8;
    for (int kt = 0; kt < 4; ++kt) {
        short8 af = *(const short8*)&Ash[w * 16 + cl][kt * 32 + kh * 8];
#pragma unroll
        for (int n = 0; n < 8; ++n) {
            short8 bf = *(const short8*)(wb + (size_t)n * 16 * C_H + kt * 32);
            acc[n] = __builtin_amdgcn_mfma_f32_16x16x32_bf16(af, bf, acc[n], 0, 0, 0);
        }
    }

    float pss[8], pqs[8];
#pragma unroll
    for (int n = 0; n < 8; ++n) {
        float s = 0.f, q = 0.f;
#pragma unroll
        for (int j = 0; j < 4; ++j) {
            float z = acc[n][j];
            z = z > 0.f ? z : SLOPE * z;
            s += z; q += z * z;
        }
        s += __shfl_xor(s, 16); s += __shfl_xor(s, 32);
        q += __shfl_xor(q, 16); q += __shfl_xor(q, 32);
        pss[n] = s; pqs[n] = q;
    }
    if (l < 16) {
#pragma unroll
        for (int n = 0; n < 8; ++n) {
            sS[w][n * 16 + l] = pss[n];
            sQ[w][n * 16 + l] = pqs[n];
        }
    }
    __syncthreads();
    if (tid < 128) {
        float s = sS[0][tid] + sS[1][tid] + sS[2][tid] + sS[3][tid];
        float q = sQ[0][tid] + sQ[1][tid] + sQ[2][tid] + sQ[3][tid];
        ps[blockIdx.x * C_H + tid] = s;
        pq[blockIdx.x * C_H + tid] = q;
    }
}

// ---------------------------------------------------------------------------
// GEMM2b: recompute z2 (same staging), lrelu + BN2 affine, write d_out in
// place (block reads only its own 64 rows -> race-free). Copies pos/batch.
// ---------------------------------------------------------------------------
__global__ __launch_bounds__(256) void k_g2b(float* __restrict__ h,
                                             const unsigned short* __restrict__ Wbf,
                                             const float* __restrict__ b2,
                                             const float* __restrict__ a1,
                                             const float* __restrict__ c1,
                                             const float* __restrict__ a2,
                                             const float* __restrict__ c2,
                                             const float* __restrict__ pos_skip,
                                             const int* __restrict__ batch_skip,
                                             float* __restrict__ out_pos,
                                             float* __restrict__ out_batch) {
    __shared__ __align__(16) unsigned short Ash[64][136];

    int r0 = blockIdx.x * 64;
    int tid = threadIdx.x;
    int l = tid & 63, w = tid >> 6;

    if (tid < 192) out_pos[(size_t)r0 * 3 + tid] = pos_skip[(size_t)r0 * 3 + tid];
    if (tid < 64)  out_batch[r0 + tid] = (float)batch_skip[r0 + tid];

    const float* src = h + (size_t)r0 * C_H;
    for (int i = tid * 4; i < 64 * C_H; i += 1024) {
        float4 v = *(const float4*)&src[i];
        int r = i >> 7, c = i & 127;
        float4 av = *(const float4*)&a1[c];
        float4 cv = *(const float4*)&c1[c];
        unsigned lo = (unsigned)f2bf(fmaf(av.x, v.x, cv.x)) |
                      ((unsigned)f2bf(fmaf(av.y, v.y, cv.y)) << 16);
        unsigned hi = (unsigned)f2bf(fmaf(av.z, v.z, cv.z)) |
                      ((unsigned)f2bf(fmaf(av.w, v.w, cv.w)) << 16);
        *(uint2*)&Ash[r][c] = make_uint2(lo, hi);
    }
    __syncthreads();

    int cl = l & 15, kh = l >> 4;
    f32x4 acc[8];
#pragma unroll
    for (int n = 0; n < 8; ++n) {
        float bv = b2[n * 16 + cl];
        acc[n][0] = bv; acc[n][1] = bv; acc[n][2] = bv; acc[n][3] = bv;
    }
    const unsigned short* wb = Wbf + (size_t)cl * C_H + kh * 8;
    for (int kt = 0; kt < 4; ++kt) {
        short8 af = *(const short8*)&Ash[w * 16 + cl][kt * 32 + kh * 8];
#pragma unroll
        for (int n = 0; n < 8; ++n) {
            short8 bf = *(const short8*)(wb + (size_t)n * 16 * C_H + kt * 32);
            acc[n] = __builtin_amdgcn_mfma_f32_16x16x32_bf16(af, bf, acc[n], 0, 0, 0);
        }
    }

#pragma unroll
    for (int n = 0; n < 8; ++n) {
        int col = n * 16 + cl;
        float av = a2[col], cv = c2[col];
#pragma unroll
        for (int j = 0; j < 4; ++j) {
            int row = r0 + w * 16 + kh * 4 + j;
            float z = acc[n][j];
            z = z > 0.f ? z : SLOPE * z;
            h[(size_t)row * C_H + col] = av * z + cv;
        }
    }
}

// ---------------------------------------------------------------------------
extern "C" void kernel_launch(void* const* d_in, const int* in_sizes, int n_in,
                              void* d_out, int out_size, void* d_ws, size_t ws_size,
                              hipStream_t stream) {
    const float* x          = (const float*)d_in[0];
    const float* pos        = (const float*)d_in[1];
    const float* x_skip     = (const float*)d_in[3];
    const float* pos_skip   = (const float*)d_in[4];
    const int*   batch_skip = (const int*)d_in[5];
    const float* W1  = (const float*)d_in[6];
    const float* b1  = (const float*)d_in[7];
    const float* g1  = (const float*)d_in[8];
    const float* be1 = (const float*)d_in[9];
    const float* W2  = (const float*)d_in[10];
    const float* b2  = (const float*)d_in[11];
    const float* g2  = (const float*)d_in[12];
    const float* be2 = (const float*)d_in[13];

    float* out_h     = (float*)d_out;
    float* out_pos   = out_h + (size_t)N_ROWS * C_H;
    float* out_batch = out_pos + (size_t)N_ROWS * 3;

    float* wsf = (float*)d_ws;
    float4* pos4         = (float4*)wsf;                         // 65536 floats
    unsigned short* W1bf = (unsigned short*)(wsf + 65536);       // 24576 us
    unsigned short* W2bf = (unsigned short*)(wsf + 77824);       // 16384 us
    float* p1s = wsf + 86016;                                    // 131072
    float* p1q = p1s + 131072;
    float* p2s = p1q + 131072;
    float* p2q = p2s + 131072;
    float* a1g = p2q + 131072;
    float* c1g = a1g + 128;
    float* a2g = c1g + 128;
    float* c2g = a2g + 128;

    k_prep<<<64, 256, 0, stream>>>(W1, W1bf, W2, W2bf, pos, pos4);
    k_fused1<<<GEMM_BLOCKS, 256, 0, stream>>>(pos4, pos_skip, x, x_skip, W1bf, b1,
                                              out_h, p1s, p1q);
    k_reduce<<<C_H, 256, 0, stream>>>(p1s, p1q, g1, be1, a1g, c1g);
    k_g2a<<<GEMM_BLOCKS, 256, 0, stream>>>(out_h, W2bf, b2, a1g, c1g, p2s, p2q);
    k_reduce<<<C_H, 256, 0, stream>>>(p2s, p2q, g2, be2, a2g, c2g);
    k_g2b<<<GEMM_BLOCKS, 256, 0, stream>>>(out_h, W2bf, b2, a1g, c1g, a2g, c2g,
                                           pos_skip, batch_skip, out_pos, out_batch);
}

// Round 12
// 155.145 us; speedup vs baseline: 1.4144x; 1.0474x over previous
//
#include <hip/hip_runtime.h>
#include <math.h>

#define NB 8
#define N_SRC 2048
#define N_DST 8192
#define C_SRC 128
#define C_SKIP 64
#define C_IN 192
#define C_H 128
#define N_ROWS (NB * N_DST)   /* 65536 */
#define BN_EPS 1e-5f
#define SLOPE 0.01f
#define GEMM_BLOCKS (N_ROWS / 64)   /* 1024 */

using short8 = __attribute__((ext_vector_type(8))) short;
using f32x4  = __attribute__((ext_vector_type(4))) float;
using sf16   = __attribute__((ext_vector_type(16))) float;

static __device__ __forceinline__ unsigned short f2bf(float f) {
    unsigned u = __builtin_bit_cast(unsigned, f);
    u = u + 0x7FFFu + ((u >> 16) & 1u);   // round-to-nearest-even
    return (unsigned short)(u >> 16);
}

// ---------------------------------------------------------------------------
// Prep: W1,W2 fp32 -> bf16 ([out][in] K-contiguous); pos -> float4 array.
// ---------------------------------------------------------------------------
__global__ __launch_bounds__(256) void k_prep(const float* __restrict__ W1,
                                              unsigned short* __restrict__ W1bf,
                                              const float* __restrict__ W2,
                                              unsigned short* __restrict__ W2bf,
                                              const float* __restrict__ pos,
                                              float4* __restrict__ pos4) {
    int gid = blockIdx.x * 256 + threadIdx.x;
    int stride = gridDim.x * 256;
    for (int i = gid; i < C_H * C_IN; i += stride) W1bf[i] = f2bf(W1[i]);
    for (int i = gid; i < C_H * C_H; i += stride)  W2bf[i] = f2bf(W2[i]);
    for (int p = gid; p < NB * N_SRC; p += stride) {
        pos4[p] = make_float4(pos[p * 3 + 0], pos[p * 3 + 1], pos[p * 3 + 2], 0.f);
    }
}

// ---------------------------------------------------------------------------
// KNN scan kernel: block = 64 dst rows x 8 waves (512 thr). Wave v scans a
// 256-pt segment via s_load_dwordx16 (scalar pipe feeds coords; inner loop
// is ~6 VALU + rarely-taken insert). 8 waves/SIMD hide the SMEM waits.
// Merge 24 candidates -> knn_idx / normalized knn_w in ws.
// ---------------------------------------------------------------------------
__global__ __launch_bounds__(512, 8) void k_knn(const float4* __restrict__ pos4,
                                                const float* __restrict__ pos_skip,
                                                int* __restrict__ knn_idx,
                                                float* __restrict__ knn_w) {
    __shared__ float cd[8][64][3];
    __shared__ int   ci[8][64][3];

    int tid = threadIdx.x;
    int l = tid & 63;
    int v = __builtin_amdgcn_readfirstlane(tid >> 6);  // uniform wave id -> SGPR addr
    int cloud = blockIdx.x >> 7;             // 128 blocks of 64 rows per cloud
    int r0 = blockIdx.x * 64;

    int dst = r0 + l;
    float px = pos_skip[dst * 3 + 0];
    float py = pos_skip[dst * 3 + 1];
    float pz = pos_skip[dst * 3 + 2];

    float rr0 = 3.4e38f, rr1 = 3.4e38f, rr2 = 3.4e38f;
    int   ii0 = 0, ii1 = 0, ii2 = 0;

    const char* sp = (const char*)(pos4 + (cloud << 11) + (v << 8));
    for (int g = 0; g < 32; ++g) {           // 32 groups x 8 points
        sf16 A, B;
        asm volatile("s_load_dwordx16 %0, %2, 0x0\n\t"
                     "s_load_dwordx16 %1, %2, 0x40\n\t"
                     "s_waitcnt lgkmcnt(0)"
                     : "=s"(A), "=s"(B)
                     : "s"(sp));
        sp += 128;
        int jb = (v << 8) + g * 8;
#pragma unroll
        for (int k = 0; k < 4; ++k) {
            float dx = px - A[4 * k], dy = py - A[4 * k + 1], dz = pz - A[4 * k + 2];
            float d = fmaf(dx, dx, fmaf(dy, dy, dz * dz));
            if (d < rr2) {
                int jj = jb + k;
                bool c0 = d < rr0, c1 = d < rr1;
                ii2 = c1 ? ii1 : jj;              rr2 = c1 ? rr1 : d;
                ii1 = c1 ? (c0 ? ii0 : jj) : ii1; rr1 = c1 ? (c0 ? rr0 : d) : rr1;
                ii0 = c0 ? jj : ii0;              rr0 = c0 ? d : rr0;
            }
        }
#pragma unroll
        for (int k = 0; k < 4; ++k) {
            float dx = px - B[4 * k], dy = py - B[4 * k + 1], dz = pz - B[4 * k + 2];
            float d = fmaf(dx, dx, fmaf(dy, dy, dz * dz));
            if (d < rr2) {
                int jj = jb + 4 + k;
                bool c0 = d < rr0, c1 = d < rr1;
                ii2 = c1 ? ii1 : jj;              rr2 = c1 ? rr1 : d;
                ii1 = c1 ? (c0 ? ii0 : jj) : ii1; rr1 = c1 ? (c0 ? rr0 : d) : rr1;
                ii0 = c0 ? jj : ii0;              rr0 = c0 ? d : rr0;
            }
        }
    }
    cd[v][l][0] = rr0; ci[v][l][0] = ii0;
    cd[v][l][1] = rr1; ci[v][l][1] = ii1;
    cd[v][l][2] = rr2; ci[v][l][2] = ii2;
    __syncthreads();

    // merge 24 candidates per dst (ascending wave = ascending index range)
    if (tid < 64) {
        float e0 = 3.4e38f, e1 = 3.4e38f, e2 = 3.4e38f;
        int   m0 = 0, m1 = 0, m2 = 0;
#pragma unroll
        for (int s = 0; s < 8; ++s) {
#pragma unroll
            for (int t = 0; t < 3; ++t) {
                float d = cd[s][tid][t];
                int  jj = ci[s][tid][t];
                if (d < e2) {
                    bool c0 = d < e0, c1 = d < e1;
                    m2 = c1 ? m1 : jj;            e2 = c1 ? e1 : d;
                    m1 = c1 ? (c0 ? m0 : jj) : m1; e1 = c1 ? (c0 ? e0 : d) : e1;
                    m0 = c0 ? jj : m0;            e0 = c0 ? d : e0;
                }
            }
        }
        float w0 = 1.f / fmaxf(e0, 1e-16f);
        float w1 = 1.f / fmaxf(e1, 1e-16f);
        float w2 = 1.f / fmaxf(e2, 1e-16f);
        float inv = 1.f / (w0 + w1 + w2);
        int row = r0 + tid;
        knn_idx[row * 3 + 0] = m0;
        knn_idx[row * 3 + 1] = m1;
        knn_idx[row * 3 + 2] = m2;
        knn_w[row * 3 + 0] = w0 * inv;
        knn_w[row * 3 + 1] = w1 * inv;
        knn_w[row * 3 + 2] = w2 * inv;
    }
}

// ---------------------------------------------------------------------------
// GEMM1: gather+interp A-tile bf16 from knn results; MFMA vs W1bf; lrelu;
// h1 fp32 -> out; BN1 partial sums.
// ---------------------------------------------------------------------------
__global__ __launch_bounds__(256) void k_gemm1(const float* __restrict__ x,
                                               const float* __restrict__ x_skip,
                                               const int* __restrict__ knn_idx,
                                               const float* __restrict__ knn_w,
                                               const unsigned short* __restrict__ Wbf,
                                               const float* __restrict__ bias,
                                               float* __restrict__ out,
                                               float* __restrict__ ps,
                                               float* __restrict__ pq) {
    __shared__ __align__(16) unsigned short Ash[64][200];
    __shared__ float sS[4][128];
    __shared__ float sQ[4][128];

    int tid = threadIdx.x;
    int l = tid & 63;
    int w = __builtin_amdgcn_readfirstlane(tid >> 6);
    int cloud = blockIdx.x >> 7;
    int r0 = blockIdx.x * 64;

    const float* xb = x + (size_t)cloud * N_SRC * C_SRC;
    for (int rr = w * 16; rr < w * 16 + 16; ++rr) {
        int row = r0 + rr;
        int j0 = knn_idx[row * 3 + 0];
        int j1 = knn_idx[row * 3 + 1];
        int j2 = knn_idx[row * 3 + 2];
        float w0 = knn_w[row * 3 + 0];
        float w1 = knn_w[row * 3 + 1];
        float w2 = knn_w[row * 3 + 2];
        const float2* x0v = (const float2*)(xb + (size_t)j0 * C_SRC);
        const float2* x1v = (const float2*)(xb + (size_t)j1 * C_SRC);
        const float2* x2v = (const float2*)(xb + (size_t)j2 * C_SRC);
        float2 a = x0v[l], b = x1v[l], c = x2v[l];
        float v0 = w0 * a.x + w1 * b.x + w2 * c.x;
        float v1 = w0 * a.y + w1 * b.y + w2 * c.y;
        ((unsigned*)&Ash[rr][0])[l] = (unsigned)f2bf(v0) | ((unsigned)f2bf(v1) << 16);
        Ash[rr][128 + l] = f2bf(x_skip[(size_t)row * C_SKIP + l]);
    }
    // waves read only their own 16-row slab -> no barrier needed

    int cl = l & 15, kh = l >> 4;
    f32x4 acc[8];
#pragma unroll
    for (int n = 0; n < 8; ++n) {
        float bv = bias[n * 16 + cl];
        acc[n][0] = bv; acc[n][1] = bv; acc[n][2] = bv; acc[n][3] = bv;
    }
    const unsigned short* wb = Wbf + (size_t)cl * C_IN + kh * 8;
    for (int kt = 0; kt < 6; ++kt) {
        short8 af = *(const short8*)&Ash[w * 16 + cl][kt * 32 + kh * 8];
#pragma unroll
        for (int n = 0; n < 8; ++n) {
            short8 bf = *(const short8*)(wb + (size_t)n * 16 * C_IN + kt * 32);
            acc[n] = __builtin_amdgcn_mfma_f32_16x16x32_bf16(af, bf, acc[n], 0, 0, 0);
        }
    }

    float pss[8], pqs[8];
#pragma unroll
    for (int n = 0; n < 8; ++n) {
        float s = 0.f, q = 0.f;
        int col = n * 16 + cl;
#pragma unroll
        for (int j = 0; j < 4; ++j) {
            int row = r0 + w * 16 + kh * 4 + j;
            float z = acc[n][j];
            z = z > 0.f ? z : SLOPE * z;
            out[(size_t)row * C_H + col] = z;
            s += z; q += z * z;
        }
        s += __shfl_xor(s, 16); s += __shfl_xor(s, 32);
        q += __shfl_xor(q, 16); q += __shfl_xor(q, 32);
        pss[n] = s; pqs[n] = q;
    }
    if (l < 16) {
#pragma unroll
        for (int n = 0; n < 8; ++n) {
            sS[w][n * 16 + l] = pss[n];
            sQ[w][n * 16 + l] = pqs[n];
        }
    }
    __syncthreads();
    if (tid < 128) {
        float s = sS[0][tid] + sS[1][tid] + sS[2][tid] + sS[3][tid];
        float q = sQ[0][tid] + sQ[1][tid] + sQ[2][tid] + sQ[3][tid];
        ps[blockIdx.x * C_H + tid] = s;
        pq[blockIdx.x * C_H + tid] = q;
    }
}

// ---------------------------------------------------------------------------
// Per-channel reduce of block partials -> BN affine
// ---------------------------------------------------------------------------
__global__ __launch_bounds__(256) void k_reduce(const float* __restrict__ ps,
                                                const float* __restrict__ pq,
                                                const float* __restrict__ g,
                                                const float* __restrict__ be,
                                                float* __restrict__ a_out,
                                                float* __restrict__ c_out) {
    int col = blockIdx.x;
    float s = 0.f, q = 0.f;
    for (int b = threadIdx.x; b < GEMM_BLOCKS; b += 256) {
        s += ps[b * C_H + col];
        q += pq[b * C_H + col];
    }
    for (int off = 32; off; off >>= 1) {
        s += __shfl_down(s, off);
        q += __shfl_down(q, off);
    }
    __shared__ float rs[4], rq[4];
    if ((threadIdx.x & 63) == 0) { rs[threadIdx.x >> 6] = s; rq[threadIdx.x >> 6] = q; }
    __syncthreads();
    if (threadIdx.x == 0) {
        s = rs[0] + rs[1] + rs[2] + rs[3];
        q = rq[0] + rq[1] + rq[2] + rq[3];
        float mean = s / (float)N_ROWS;
        float var  = q / (float)N_ROWS - mean * mean;
        float a = g[col] * rsqrtf(var + BN_EPS);
        a_out[col] = a;
        c_out[col] = be[col] - mean * a;
    }
}

// ---------------------------------------------------------------------------
// GEMM2a: stats-only pass. Stage Ash = bf16(a1*h1 + c1) (BN1 applied here);
// z2 = Ash@W2bf^T + b2; lrelu; BN2 partials. No store.
// ---------------------------------------------------------------------------
__global__ __launch_bounds__(256) void k_g2a(const float* __restrict__ h,
                                             const unsigned short* __restrict__ Wbf,
                                             const float* __restrict__ b2,
                                             const float* __restrict__ a1,
                                             const float* __restrict__ c1,
                                             float* __restrict__ ps,
                                             float* __restrict__ pq) {
    __shared__ __align__(16) unsigned short Ash[64][136];
    __shared__ float sS[4][128];
    __shared__ float sQ[4][128];

    int r0 = blockIdx.x * 64;
    int tid = threadIdx.x;
    int l = tid & 63, w = tid >> 6;

    const float* src = h + (size_t)r0 * C_H;
    for (int i = tid * 4; i < 64 * C_H; i += 1024) {
        float4 v = *(const float4*)&src[i];
        int r = i >> 7, c = i & 127;
        float4 av = *(const float4*)&a1[c];
        float4 cv = *(const float4*)&c1[c];
        unsigned lo = (unsigned)f2bf(fmaf(av.x, v.x, cv.x)) |
                      ((unsigned)f2bf(fmaf(av.y, v.y, cv.y)) << 16);
        unsigned hi = (unsigned)f2bf(fmaf(av.z, v.z, cv.z)) |
                      ((unsigned)f2bf(fmaf(av.w, v.w, cv.w)) << 16);
        *(uint2*)&Ash[r][c] = make_uint2(lo, hi);
    }
    __syncthreads();

    int cl = l & 15, kh = l >> 4;
    f32x4 acc[8];
#pragma unroll
    for (int n = 0; n < 8; ++n) {
        float bv = b2[n * 16 + cl];
        acc[n][0] = bv; acc[n][1] = bv; acc[n][2] = bv; acc[n][3] = bv;
    }
    const unsigned short* wb = Wbf + (size_t)cl * C_H + kh * 8;
    for (int kt = 0; kt < 4; ++kt) {
        short8 af = *(const short8*)&Ash[w * 16 + cl][kt * 32 + kh * 8];
#pragma unroll
        for (int n = 0; n < 8; ++n) {
            short8 bf = *(const short8*)(wb + (size_t)n * 16 * C_H + kt * 32);
            acc[n] = __builtin_amdgcn_mfma_f32_16x16x32_bf16(af, bf, acc[n], 0, 0, 0);
        }
    }

    float pss[8], pqs[8];
#pragma unroll
    for (int n = 0; n < 8; ++n) {
        float s = 0.f, q = 0.f;
#pragma unroll
        for (int j = 0; j < 4; ++j) {
            float z = acc[n][j];
            z = z > 0.f ? z : SLOPE * z;
            s += z; q += z * z;
        }
        s += __shfl_xor(s, 16); s += __shfl_xor(s, 32);
        q += __shfl_xor(q, 16); q += __shfl_xor(q, 32);
        pss[n] = s; pqs[n] = q;
    }
    if (l < 16) {
#pragma unroll
        for (int n = 0; n < 8; ++n) {
            sS[w][n * 16 + l] = pss[n];
            sQ[w][n * 16 + l] = pqs[n];
        }
    }
    __syncthreads();
    if (tid < 128) {
        float s = sS[0][tid] + sS[1][tid] + sS[2][tid] + sS[3][tid];
        float q = sQ[0][tid] + sQ[1][tid] + sQ[2][tid] + sQ[3][tid];
        ps[blockIdx.x * C_H + tid] = s;
        pq[blockIdx.x * C_H + tid] = q;
    }
}

// ---------------------------------------------------------------------------
// GEMM2b: recompute z2 (same staging), lrelu + BN2 affine, write d_out in
// place (block reads only its own 64 rows -> race-free). Copies pos/batch.
// ---------------------------------------------------------------------------
__global__ __launch_bounds__(256) void k_g2b(float* __restrict__ h,
                                             const unsigned short* __restrict__ Wbf,
                                             const float* __restrict__ b2,
                                             const float* __restrict__ a1,
                                             const float* __restrict__ c1,
                                             const float* __restrict__ a2,
                                             const float* __restrict__ c2,
                                             const float* __restrict__ pos_skip,
                                             const int* __restrict__ batch_skip,
                                             float* __restrict__ out_pos,
                                             float* __restrict__ out_batch) {
    __shared__ __align__(16) unsigned short Ash[64][136];

    int r0 = blockIdx.x * 64;
    int tid = threadIdx.x;
    int l = tid & 63, w = tid >> 6;

    if (tid < 192) out_pos[(size_t)r0 * 3 + tid] = pos_skip[(size_t)r0 * 3 + tid];
    if (tid < 64)  out_batch[r0 + tid] = (float)batch_skip[r0 + tid];

    const float* src = h + (size_t)r0 * C_H;
    for (int i = tid * 4; i < 64 * C_H; i += 1024) {
        float4 v = *(const float4*)&src[i];
        int r = i >> 7, c = i & 127;
        float4 av = *(const float4*)&a1[c];
        float4 cv = *(const float4*)&c1[c];
        unsigned lo = (unsigned)f2bf(fmaf(av.x, v.x, cv.x)) |
                      ((unsigned)f2bf(fmaf(av.y, v.y, cv.y)) << 16);
        unsigned hi = (unsigned)f2bf(fmaf(av.z, v.z, cv.z)) |
                      ((unsigned)f2bf(fmaf(av.w, v.w, cv.w)) << 16);
        *(uint2*)&Ash[r][c] = make_uint2(lo, hi);
    }
    __syncthreads();

    int cl = l & 15, kh = l >> 4;
    f32x4 acc[8];
#pragma unroll
    for (int n = 0; n < 8; ++n) {
        float bv = b2[n * 16 + cl];
        acc[n][0] = bv; acc[n][1] = bv; acc[n][2] = bv; acc[n][3] = bv;
    }
    const unsigned short* wb = Wbf + (size_t)cl * C_H + kh * 8;
    for (int kt = 0; kt < 4; ++kt) {
        short8 af = *(const short8*)&Ash[w * 16 + cl][kt * 32 + kh * 8];
#pragma unroll
        for (int n = 0; n < 8; ++n) {
            short8 bf = *(const short8*)(wb + (size_t)n * 16 * C_H + kt * 32);
            acc[n] = __builtin_amdgcn_mfma_f32_16x16x32_bf16(af, bf, acc[n], 0, 0, 0);
        }
    }

#pragma unroll
    for (int n = 0; n < 8; ++n) {
        int col = n * 16 + cl;
        float av = a2[col], cv = c2[col];
#pragma unroll
        for (int j = 0; j < 4; ++j) {
            int row = r0 + w * 16 + kh * 4 + j;
            float z = acc[n][j];
            z = z > 0.f ? z : SLOPE * z;
            h[(size_t)row * C_H + col] = av * z + cv;
        }
    }
}

// ---------------------------------------------------------------------------
extern "C" void kernel_launch(void* const* d_in, const int* in_sizes, int n_in,
                              void* d_out, int out_size, void* d_ws, size_t ws_size,
                              hipStream_t stream) {
    const float* x          = (const float*)d_in[0];
    const float* pos        = (const float*)d_in[1];
    const float* x_skip     = (const float*)d_in[3];
    const float* pos_skip   = (const float*)d_in[4];
    const int*   batch_skip = (const int*)d_in[5];
    const float* W1  = (const float*)d_in[6];
    const float* b1  = (const float*)d_in[7];
    const float* g1  = (const float*)d_in[8];
    const float* be1 = (const float*)d_in[9];
    const float* W2  = (const float*)d_in[10];
    const float* b2  = (const float*)d_in[11];
    const float* g2  = (const float*)d_in[12];
    const float* be2 = (const float*)d_in[13];

    float* out_h     = (float*)d_out;
    float* out_pos   = out_h + (size_t)N_ROWS * C_H;
    float* out_batch = out_pos + (size_t)N_ROWS * 3;

    float* wsf = (float*)d_ws;
    float4* pos4         = (float4*)wsf;                         // 65536 floats
    unsigned short* W1bf = (unsigned short*)(wsf + 65536);       // 24576 us
    unsigned short* W2bf = (unsigned short*)(wsf + 77824);       // 16384 us
    float* p1s = wsf + 86016;                                    // 131072
    float* p1q = p1s + 131072;
    float* p2s = p1q + 131072;
    float* p2q = p2s + 131072;
    float* a1g = p2q + 131072;
    float* c1g = a1g + 128;
    float* a2g = c1g + 128;
    float* c2g = a2g + 128;
    int*   knn_idx = (int*)(c2g + 128);                          // 196608 ints
    float* knn_w   = (float*)(knn_idx + 196608);                 // 196608 floats

    k_prep<<<64, 256, 0, stream>>>(W1, W1bf, W2, W2bf, pos, pos4);
    k_knn<<<GEMM_BLOCKS, 512, 0, stream>>>(pos4, pos_skip, knn_idx, knn_w);
    k_gemm1<<<GEMM_BLOCKS, 256, 0, stream>>>(x, x_skip, knn_idx, knn_w, W1bf, b1,
                                             out_h, p1s, p1q);
    k_reduce<<<C_H, 256, 0, stream>>>(p1s, p1q, g1, be1, a1g, c1g);
    k_g2a<<<GEMM_BLOCKS, 256, 0, stream>>>(out_h, W2bf, b2, a1g, c1g, p2s, p2q);
    k_reduce<<<C_H, 256, 0, stream>>>(p2s, p2q, g2, be2, a2g, c2g);
    k_g2b<<<GEMM_BLOCKS, 256, 0, stream>>>(out_h, W2bf, b2, a1g, c1g, a2g, c2g,
                                           pos_skip, batch_skip, out_pos, out_batch);
}

// Round 13
// 124.411 us; speedup vs baseline: 1.7637x; 1.2470x over previous
//
#include <hip/hip_runtime.h>
#include <math.h>

#define NB 8
#define N_SRC 2048
#define N_DST 8192
#define C_SRC 128
#define C_SKIP 64
#define C_IN 192
#define C_H 128
#define N_ROWS (NB * N_DST)   /* 65536 */
#define BN_EPS 1e-5f
#define SLOPE 0.01f
#define GEMM_BLOCKS (N_ROWS / 64)   /* 1024 */

using short8 = __attribute__((ext_vector_type(8))) short;
using f32x4  = __attribute__((ext_vector_type(4))) float;
using sf16   = __attribute__((ext_vector_type(16))) float;

static __device__ __forceinline__ unsigned short f2bf(float f) {
    unsigned u = __builtin_bit_cast(unsigned, f);
    u = u + 0x7FFFu + ((u >> 16) & 1u);   // round-to-nearest-even
    return (unsigned short)(u >> 16);
}

// ---------------------------------------------------------------------------
// Prep: W1,W2 fp32 -> bf16; pos -> float4 array; pos/batch output copies.
// ---------------------------------------------------------------------------
__global__ __launch_bounds__(256) void k_prep(const float* __restrict__ W1,
                                              unsigned short* __restrict__ W1bf,
                                              const float* __restrict__ W2,
                                              unsigned short* __restrict__ W2bf,
                                              const float* __restrict__ pos,
                                              float4* __restrict__ pos4,
                                              const float* __restrict__ pos_skip,
                                              const int* __restrict__ batch_skip,
                                              float* __restrict__ out_pos,
                                              float* __restrict__ out_batch) {
    int gid = blockIdx.x * 256 + threadIdx.x;
    int stride = gridDim.x * 256;
    for (int i = gid; i < C_H * C_IN; i += stride) W1bf[i] = f2bf(W1[i]);
    for (int i = gid; i < C_H * C_H; i += stride)  W2bf[i] = f2bf(W2[i]);
    for (int p = gid; p < NB * N_SRC; p += stride) {
        pos4[p] = make_float4(pos[p * 3 + 0], pos[p * 3 + 1], pos[p * 3 + 2], 0.f);
    }
    for (int i = gid; i < N_ROWS * 3 / 4; i += stride) {
        ((float4*)out_pos)[i] = ((const float4*)pos_skip)[i];
    }
    for (int i = gid; i < N_ROWS; i += stride) {
        out_batch[i] = (float)batch_skip[i];
    }
}

// ---------------------------------------------------------------------------
// Fused KNN + GEMM1, 512 threads (8 waves).
// Scan: wave v scans a 256-pt segment via s_load_dwordx16 (scalar pipe),
//       branchy top-3 insert (verified r12 inner loop, bit-identical).
// Merge 24 candidates -> midx/mw in LDS.
// Gather: 8 waves x 8 rows -> bf16 A-tile.  MFMA1 + lrelu + BN1 partials on
// waves 0-3.  h1 fp32 -> out (d_out h region).
// ---------------------------------------------------------------------------
__global__ __launch_bounds__(512, 8) void k_fused1(
    const float4* __restrict__ pos4, const float* __restrict__ pos_skip,
    const float* __restrict__ x, const float* __restrict__ x_skip,
    const unsigned short* __restrict__ Wbf, const float* __restrict__ bias,
    float* __restrict__ out, float* __restrict__ ps, float* __restrict__ pq) {
    __shared__ __align__(16) unsigned short Ash[64][200];  // 25600 B (cd/ci overlay)
    __shared__ float sS[4][128];
    __shared__ float sQ[4][128];
    __shared__ int   midx[64][3];
    __shared__ float mw[64][3];

    float* cd = (float*)&Ash[0][0];                  // [8*64*3] floats (6144 B)
    int*   ci = (int*)((char*)&Ash[0][0] + 6144);    // [8*64*3] ints   (6144 B)

    int tid = threadIdx.x;
    int l = tid & 63;
    int v = __builtin_amdgcn_readfirstlane(tid >> 6);  // uniform wave id 0..7
    int cloud = blockIdx.x >> 7;
    int r0 = blockIdx.x * 64;

    // ---------------- scan: 8 waves x 256 points ----------------
    int dst = r0 + l;
    float px = pos_skip[dst * 3 + 0];
    float py = pos_skip[dst * 3 + 1];
    float pz = pos_skip[dst * 3 + 2];

    float rr0 = 3.4e38f, rr1 = 3.4e38f, rr2 = 3.4e38f;
    int   ii0 = 0, ii1 = 0, ii2 = 0;

    const char* sp = (const char*)(pos4 + (cloud << 11) + (v << 8));
    for (int g = 0; g < 32; ++g) {           // 32 groups x 8 points
        sf16 A, B;
        asm volatile("s_load_dwordx16 %0, %2, 0x0\n\t"
                     "s_load_dwordx16 %1, %2, 0x40\n\t"
                     "s_waitcnt lgkmcnt(0)"
                     : "=s"(A), "=s"(B)
                     : "s"(sp));
        sp += 128;
        int jb = (v << 8) + g * 8;
#pragma unroll
        for (int k = 0; k < 4; ++k) {
            float dx = px - A[4 * k], dy = py - A[4 * k + 1], dz = pz - A[4 * k + 2];
            float d = fmaf(dx, dx, fmaf(dy, dy, dz * dz));
            if (d < rr2) {
                int jj = jb + k;
                bool c0 = d < rr0, c1 = d < rr1;
                ii2 = c1 ? ii1 : jj;              rr2 = c1 ? rr1 : d;
                ii1 = c1 ? (c0 ? ii0 : jj) : ii1; rr1 = c1 ? (c0 ? rr0 : d) : rr1;
                ii0 = c0 ? jj : ii0;              rr0 = c0 ? d : rr0;
            }
        }
#pragma unroll
        for (int k = 0; k < 4; ++k) {
            float dx = px - B[4 * k], dy = py - B[4 * k + 1], dz = pz - B[4 * k + 2];
            float d = fmaf(dx, dx, fmaf(dy, dy, dz * dz));
            if (d < rr2) {
                int jj = jb + 4 + k;
                bool c0 = d < rr0, c1 = d < rr1;
                ii2 = c1 ? ii1 : jj;              rr2 = c1 ? rr1 : d;
                ii1 = c1 ? (c0 ? ii0 : jj) : ii1; rr1 = c1 ? (c0 ? rr0 : d) : rr1;
                ii0 = c0 ? jj : ii0;              rr0 = c0 ? d : rr0;
            }
        }
    }
    cd[(v * 64 + l) * 3 + 0] = rr0; ci[(v * 64 + l) * 3 + 0] = ii0;
    cd[(v * 64 + l) * 3 + 1] = rr1; ci[(v * 64 + l) * 3 + 1] = ii1;
    cd[(v * 64 + l) * 3 + 2] = rr2; ci[(v * 64 + l) * 3 + 2] = ii2;
    __syncthreads();

    // ---------------- merge 24 candidates per dst ----------------
    if (tid < 64) {
        float e0 = 3.4e38f, e1 = 3.4e38f, e2 = 3.4e38f;
        int   m0 = 0, m1 = 0, m2 = 0;
#pragma unroll
        for (int s = 0; s < 8; ++s) {
#pragma unroll
            for (int t = 0; t < 3; ++t) {
                float d = cd[(s * 64 + tid) * 3 + t];
                int  jj = ci[(s * 64 + tid) * 3 + t];
                if (d < e2) {
                    bool c0 = d < e0, c1 = d < e1;
                    m2 = c1 ? m1 : jj;            e2 = c1 ? e1 : d;
                    m1 = c1 ? (c0 ? m0 : jj) : m1; e1 = c1 ? (c0 ? e0 : d) : e1;
                    m0 = c0 ? jj : m0;            e0 = c0 ? d : e0;
                }
            }
        }
        float w0 = 1.f / fmaxf(e0, 1e-16f);
        float w1 = 1.f / fmaxf(e1, 1e-16f);
        float w2 = 1.f / fmaxf(e2, 1e-16f);
        float inv = 1.f / (w0 + w1 + w2);
        midx[tid][0] = m0; midx[tid][1] = m1; midx[tid][2] = m2;
        mw[tid][0] = w0 * inv; mw[tid][1] = w1 * inv; mw[tid][2] = w2 * inv;
    }
    __syncthreads();

    // ---------------- gather: 8 waves x 8 rows -> bf16 A-tile ----------------
    const float* xb = x + (size_t)cloud * N_SRC * C_SRC;
    for (int rr = v * 8; rr < v * 8 + 8; ++rr) {
        int j0 = midx[rr][0], j1 = midx[rr][1], j2 = midx[rr][2];
        float w0 = mw[rr][0], w1 = mw[rr][1], w2 = mw[rr][2];
        const float2* x0v = (const float2*)(xb + (size_t)j0 * C_SRC);
        const float2* x1v = (const float2*)(xb + (size_t)j1 * C_SRC);
        const float2* x2v = (const float2*)(xb + (size_t)j2 * C_SRC);
        float2 a = x0v[l], b = x1v[l], c = x2v[l];
        float v0 = w0 * a.x + w1 * b.x + w2 * c.x;
        float v1 = w0 * a.y + w1 * b.y + w2 * c.y;
        ((unsigned*)&Ash[rr][0])[l] = (unsigned)f2bf(v0) | ((unsigned)f2bf(v1) << 16);
        Ash[rr][128 + l] = f2bf(x_skip[(size_t)(r0 + rr) * C_SKIP + l]);
    }
    __syncthreads();

    // ---------------- MFMA1 + epilogue (waves 0-3) ----------------
    if (v < 4) {
        int w = v;
        int cl = l & 15, kh = l >> 4;
        f32x4 acc[8];
#pragma unroll
        for (int n = 0; n < 8; ++n) {
            float bv = bias[n * 16 + cl];
            acc[n][0] = bv; acc[n][1] = bv; acc[n][2] = bv; acc[n][3] = bv;
        }
        const unsigned short* wb = Wbf + (size_t)cl * C_IN + kh * 8;
        for (int kt = 0; kt < 6; ++kt) {
            short8 af = *(const short8*)&Ash[w * 16 + cl][kt * 32 + kh * 8];
#pragma unroll
            for (int n = 0; n < 8; ++n) {
                short8 bf = *(const short8*)(wb + (size_t)n * 16 * C_IN + kt * 32);
                acc[n] = __builtin_amdgcn_mfma_f32_16x16x32_bf16(af, bf, acc[n], 0, 0, 0);
            }
        }

#pragma unroll
        for (int n = 0; n < 8; ++n) {
            float s = 0.f, q = 0.f;
            int col = n * 16 + cl;
#pragma unroll
            for (int j = 0; j < 4; ++j) {
                int row = r0 + w * 16 + kh * 4 + j;
                float z = acc[n][j];
                z = z > 0.f ? z : SLOPE * z;
                out[(size_t)row * C_H + col] = z;
                s += z; q += z * z;
            }
            s += __shfl_xor(s, 16); s += __shfl_xor(s, 32);
            q += __shfl_xor(q, 16); q += __shfl_xor(q, 32);
            if (l < 16) {
                sS[w][n * 16 + l] = s;
                sQ[w][n * 16 + l] = q;
            }
        }
    }
    __syncthreads();
    if (tid < 128) {
        float s = sS[0][tid] + sS[1][tid] + sS[2][tid] + sS[3][tid];
        float q = sQ[0][tid] + sQ[1][tid] + sQ[2][tid] + sQ[3][tid];
        ps[blockIdx.x * C_H + tid] = s;
        pq[blockIdx.x * C_H + tid] = q;
    }
}

// ---------------------------------------------------------------------------
// Per-channel reduce of block partials -> BN affine
// ---------------------------------------------------------------------------
__global__ __launch_bounds__(256) void k_reduce(const float* __restrict__ ps,
                                                const float* __restrict__ pq,
                                                const float* __restrict__ g,
                                                const float* __restrict__ be,
                                                float* __restrict__ a_out,
                                                float* __restrict__ c_out) {
    int col = blockIdx.x;
    float s = 0.f, q = 0.f;
    for (int b = threadIdx.x; b < GEMM_BLOCKS; b += 256) {
        s += ps[b * C_H + col];
        q += pq[b * C_H + col];
    }
    for (int off = 32; off; off >>= 1) {
        s += __shfl_down(s, off);
        q += __shfl_down(q, off);
    }
    __shared__ float rs[4], rq[4];
    if ((threadIdx.x & 63) == 0) { rs[threadIdx.x >> 6] = s; rq[threadIdx.x >> 6] = q; }
    __syncthreads();
    if (threadIdx.x == 0) {
        s = rs[0] + rs[1] + rs[2] + rs[3];
        q = rq[0] + rq[1] + rq[2] + rq[3];
        float mean = s / (float)N_ROWS;
        float var  = q / (float)N_ROWS - mean * mean;
        float a = g[col] * rsqrtf(var + BN_EPS);
        a_out[col] = a;
        c_out[col] = be[col] - mean * a;
    }
}

// ---------------------------------------------------------------------------
// GEMM2a: stage Ash = bf16(a1*h1 + c1); z2 = Ash@W2bf^T + b2; lrelu; BN2
// partials.  If z2bf != nullptr, also stash lrelu(z2) as bf16 (row-major,
// coalesced via LDS repack) so the final pass is elementwise.
// ---------------------------------------------------------------------------
__global__ __launch_bounds__(256) void k_g2a(const float* __restrict__ h,
                                             const unsigned short* __restrict__ Wbf,
                                             const float* __restrict__ b2,
                                             const float* __restrict__ a1,
                                             const float* __restrict__ c1,
                                             float* __restrict__ ps,
                                             float* __restrict__ pq,
                                             unsigned short* __restrict__ z2bf) {
    __shared__ __align__(16) unsigned short Ash[64][136];
    __shared__ float sS[4][128];
    __shared__ float sQ[4][128];

    int r0 = blockIdx.x * 64;
    int tid = threadIdx.x;
    int l = tid & 63, w = tid >> 6;

    const float* src = h + (size_t)r0 * C_H;
    for (int i = tid * 4; i < 64 * C_H; i += 1024) {
        float4 v = *(const float4*)&src[i];
        int r = i >> 7, c = i & 127;
        float4 av = *(const float4*)&a1[c];
        float4 cv = *(const float4*)&c1[c];
        unsigned lo = (unsigned)f2bf(fmaf(av.x, v.x, cv.x)) |
                      ((unsigned)f2bf(fmaf(av.y, v.y, cv.y)) << 16);
        unsigned hi = (unsigned)f2bf(fmaf(av.z, v.z, cv.z)) |
                      ((unsigned)f2bf(fmaf(av.w, v.w, cv.w)) << 16);
        *(uint2*)&Ash[r][c] = make_uint2(lo, hi);
    }
    __syncthreads();

    int cl = l & 15, kh = l >> 4;
    f32x4 acc[8];
#pragma unroll
    for (int n = 0; n < 8; ++n) {
        float bv = b2[n * 16 + cl];
        acc[n][0] = bv; acc[n][1] = bv; acc[n][2] = bv; acc[n][3] = bv;
    }
    const unsigned short* wb = Wbf + (size_t)cl * C_H + kh * 8;
    for (int kt = 0; kt < 4; ++kt) {
        short8 af = *(const short8*)&Ash[w * 16 + cl][kt * 32 + kh * 8];
#pragma unroll
        for (int n = 0; n < 8; ++n) {
            short8 bf = *(const short8*)(wb + (size_t)n * 16 * C_H + kt * 32);
            acc[n] = __builtin_amdgcn_mfma_f32_16x16x32_bf16(af, bf, acc[n], 0, 0, 0);
        }
    }

    float pss[8], pqs[8];
#pragma unroll
    for (int n = 0; n < 8; ++n) {
        float s = 0.f, q = 0.f;
#pragma unroll
        for (int j = 0; j < 4; ++j) {
            float z = acc[n][j];
            z = z > 0.f ? z : SLOPE * z;
            acc[n][j] = z;                // keep lrelu'd z2
            s += z; q += z * z;
        }
        s += __shfl_xor(s, 16); s += __shfl_xor(s, 32);
        q += __shfl_xor(q, 16); q += __shfl_xor(q, 32);
        pss[n] = s; pqs[n] = q;
    }

    if (z2bf) {
        __syncthreads();                  // all Ash k-loop reads complete
        unsigned short* Az = (unsigned short*)&Ash[0][0];   // packed [64][128]
#pragma unroll
        for (int n = 0; n < 8; ++n) {
            int col = n * 16 + cl;
#pragma unroll
            for (int j = 0; j < 4; ++j) {
                Az[(w * 16 + kh * 4 + j) * 128 + col] = f2bf(acc[n][j]);
            }
        }
    }
    if (l < 16) {
#pragma unroll
        for (int n = 0; n < 8; ++n) {
            sS[w][n * 16 + l] = pss[n];
            sQ[w][n * 16 + l] = pqs[n];
        }
    }
    __syncthreads();
    if (z2bf) {
        const uint4* Asrc = (const uint4*)&Ash[0][0];
        uint4* zdst = (uint4*)(z2bf + (size_t)r0 * C_H);
        for (int i = tid; i < 64 * C_H / 8; i += 256) zdst[i] = Asrc[i];
    }
    if (tid < 128) {
        float s = sS[0][tid] + sS[1][tid] + sS[2][tid] + sS[3][tid];
        float q = sQ[0][tid] + sQ[1][tid] + sQ[2][tid] + sQ[3][tid];
        ps[blockIdx.x * C_H + tid] = s;
        pq[blockIdx.x * C_H + tid] = q;
    }
}

// ---------------------------------------------------------------------------
// Final (main path): out_h = a2 * z2bf + c2, elementwise, fully coalesced.
// ---------------------------------------------------------------------------
__global__ __launch_bounds__(256) void k_final(const unsigned short* __restrict__ z2bf,
                                               const float* __restrict__ a2,
                                               const float* __restrict__ c2,
                                               float* __restrict__ out_h) {
    __shared__ float sa[128], sc[128];
    int tid = threadIdx.x;
    if (tid < 128) { sa[tid] = a2[tid]; sc[tid] = c2[tid]; }
    __syncthreads();

    int gid = blockIdx.x * 256 + tid;
    int stride = gridDim.x * 256;
    const uint4* zsrc = (const uint4*)z2bf;
    for (int i = gid; i < N_ROWS * C_H / 8; i += stride) {
        uint4 v = zsrc[i];
        int c0 = (i * 8) & 127;
        float4 o0, o1;
        o0.x = fmaf(sa[c0 + 0], __builtin_bit_cast(float, (v.x & 0xFFFFu) << 16), sc[c0 + 0]);
        o0.y = fmaf(sa[c0 + 1], __builtin_bit_cast(float, (v.x & 0xFFFF0000u)), sc[c0 + 1]);
        o0.z = fmaf(sa[c0 + 2], __builtin_bit_cast(float, (v.y & 0xFFFFu) << 16), sc[c0 + 2]);
        o0.w = fmaf(sa[c0 + 3], __builtin_bit_cast(float, (v.y & 0xFFFF0000u)), sc[c0 + 3]);
        o1.x = fmaf(sa[c0 + 4], __builtin_bit_cast(float, (v.z & 0xFFFFu) << 16), sc[c0 + 4]);
        o1.y = fmaf(sa[c0 + 5], __builtin_bit_cast(float, (v.z & 0xFFFF0000u)), sc[c0 + 5]);
        o1.z = fmaf(sa[c0 + 6], __builtin_bit_cast(float, (v.w & 0xFFFFu) << 16), sc[c0 + 6]);
        o1.w = fmaf(sa[c0 + 7], __builtin_bit_cast(float, (v.w & 0xFFFF0000u)), sc[c0 + 7]);
        *(float4*)&out_h[(size_t)i * 8]     = o0;
        *(float4*)&out_h[(size_t)i * 8 + 4] = o1;
    }
}

// ---------------------------------------------------------------------------
// GEMM2b (fallback when ws too small): recompute z2, lrelu + BN2 affine,
// in-place write; copies pos/batch (redundant with prep, harmless).
// ---------------------------------------------------------------------------
__global__ __launch_bounds__(256) void k_g2b(float* __restrict__ h,
                                             const unsigned short* __restrict__ Wbf,
                                             const float* __restrict__ b2,
                                             const float* __restrict__ a1,
                                             const float* __restrict__ c1,
                                             const float* __restrict__ a2,
                                             const float* __restrict__ c2) {
    __shared__ __align__(16) unsigned short Ash[64][136];

    int r0 = blockIdx.x * 64;
    int tid = threadIdx.x;
    int l = tid & 63, w = tid >> 6;

    const float* src = h + (size_t)r0 * C_H;
    for (int i = tid * 4; i < 64 * C_H; i += 1024) {
        float4 v = *(const float4*)&src[i];
        int r = i >> 7, c = i & 127;
        float4 av = *(const float4*)&a1[c];
        float4 cv = *(const float4*)&c1[c];
        unsigned lo = (unsigned)f2bf(fmaf(av.x, v.x, cv.x)) |
                      ((unsigned)f2bf(fmaf(av.y, v.y, cv.y)) << 16);
        unsigned hi = (unsigned)f2bf(fmaf(av.z, v.z, cv.z)) |
                      ((unsigned)f2bf(fmaf(av.w, v.w, cv.w)) << 16);
        *(uint2*)&Ash[r][c] = make_uint2(lo, hi);
    }
    __syncthreads();

    int cl = l & 15, kh = l >> 4;
    f32x4 acc[8];
#pragma unroll
    for (int n = 0; n < 8; ++n) {
        float bv = b2[n * 16 + cl];
        acc[n][0] = bv; acc[n][1] = bv; acc[n][2] = bv; acc[n][3] = bv;
    }
    const unsigned short* wb = Wbf + (size_t)cl * C_H + kh * 8;
    for (int kt = 0; kt < 4; ++kt) {
        short8 af = *(const short8*)&Ash[w * 16 + cl][kt * 32 + kh * 8];
#pragma unroll
        for (int n = 0; n < 8; ++n) {
            short8 bf = *(const short8*)(wb + (size_t)n * 16 * C_H + kt * 32);
            acc[n] = __builtin_amdgcn_mfma_f32_16x16x32_bf16(af, bf, acc[n], 0, 0, 0);
        }
    }

#pragma unroll
    for (int n = 0; n < 8; ++n) {
        int col = n * 16 + cl;
        float av = a2[col], cv = c2[col];
#pragma unroll
        for (int j = 0; j < 4; ++j) {
            int row = r0 + w * 16 + kh * 4 + j;
            float z = acc[n][j];
            z = z > 0.f ? z : SLOPE * z;
            h[(size_t)row * C_H + col] = av * z + cv;
        }
    }
}

// ---------------------------------------------------------------------------
extern "C" void kernel_launch(void* const* d_in, const int* in_sizes, int n_in,
                              void* d_out, int out_size, void* d_ws, size_t ws_size,
                              hipStream_t stream) {
    const float* x          = (const float*)d_in[0];
    const float* pos        = (const float*)d_in[1];
    const float* x_skip     = (const float*)d_in[3];
    const float* pos_skip   = (const float*)d_in[4];
    const int*   batch_skip = (const int*)d_in[5];
    const float* W1  = (const float*)d_in[6];
    const float* b1  = (const float*)d_in[7];
    const float* g1  = (const float*)d_in[8];
    const float* be1 = (const float*)d_in[9];
    const float* W2  = (const float*)d_in[10];
    const float* b2  = (const float*)d_in[11];
    const float* g2  = (const float*)d_in[12];
    const float* be2 = (const float*)d_in[13];

    float* out_h     = (float*)d_out;
    float* out_pos   = out_h + (size_t)N_ROWS * C_H;
    float* out_batch = out_pos + (size_t)N_ROWS * 3;

    float* wsf = (float*)d_ws;
    float4* pos4         = (float4*)wsf;                         // 65536 floats
    unsigned short* W1bf = (unsigned short*)(wsf + 65536);       // 24576 us
    unsigned short* W2bf = (unsigned short*)(wsf + 77824);       // 16384 us
    float* p1s = wsf + 86016;                                    // 131072
    float* p1q = p1s + 131072;
    float* p2s = p1q + 131072;
    float* p2q = p2s + 131072;
    float* a1g = p2q + 131072;
    float* c1g = a1g + 128;
    float* a2g = c1g + 128;
    float* c2g = a2g + 128;
    unsigned short* z2bf = (unsigned short*)(c2g + 128);         // 8388608 us
    size_t ws_needed = ((size_t)(610816) * 4) + (size_t)N_ROWS * C_H * 2;
    bool use_z = ws_size >= ws_needed;

    k_prep<<<256, 256, 0, stream>>>(W1, W1bf, W2, W2bf, pos, pos4,
                                    pos_skip, batch_skip, out_pos, out_batch);
    k_fused1<<<GEMM_BLOCKS, 512, 0, stream>>>(pos4, pos_skip, x, x_skip, W1bf, b1,
                                              out_h, p1s, p1q);
    k_reduce<<<C_H, 256, 0, stream>>>(p1s, p1q, g1, be1, a1g, c1g);
    k_g2a<<<GEMM_BLOCKS, 256, 0, stream>>>(out_h, W2bf, b2, a1g, c1g, p2s, p2q,
                                           use_z ? z2bf : (unsigned short*)nullptr);
    k_reduce<<<C_H, 256, 0, stream>>>(p2s, p2q, g2, be2, a2g, c2g);
    if (use_z) {
        k_final<<<1024, 256, 0, stream>>>(z2bf, a2g, c2g, out_h);
    } else {
        k_g2b<<<GEMM_BLOCKS, 256, 0, stream>>>(out_h, W2bf, b2, a1g, c1g, a2g, c2g);
    }
}

// Round 14
// 112.867 us; speedup vs baseline: 1.9442x; 1.1023x over previous
//
#include <hip/hip_runtime.h>
#include <math.h>

#define NB 8
#define N_SRC 2048
#define N_DST 8192
#define C_SRC 128
#define C_SKIP 64
#define C_IN 192
#define C_H 128
#define N_ROWS (NB * N_DST)   /* 65536 */
#define BN_EPS 1e-5f
#define SLOPE 0.01f
#define GEMM_BLOCKS (N_ROWS / 64)   /* 1024 */

using short8 = __attribute__((ext_vector_type(8))) short;
using f32x4  = __attribute__((ext_vector_type(4))) float;
using sf16   = __attribute__((ext_vector_type(16))) float;

static __device__ __forceinline__ unsigned short f2bf(float f) {
    unsigned u = __builtin_bit_cast(unsigned, f);
    u = u + 0x7FFFu + ((u >> 16) & 1u);   // round-to-nearest-even
    return (unsigned short)(u >> 16);
}
static __device__ __forceinline__ float bflo(unsigned v) {
    return __builtin_bit_cast(float, (v & 0xFFFFu) << 16);
}
static __device__ __forceinline__ float bfhi(unsigned v) {
    return __builtin_bit_cast(float, v & 0xFFFF0000u);
}

// ---------------------------------------------------------------------------
// Prep: W1,W2 fp32 -> bf16; pos -> float4 array; pos/batch output copies.
// ---------------------------------------------------------------------------
__global__ __launch_bounds__(256) void k_prep(const float* __restrict__ W1,
                                              unsigned short* __restrict__ W1bf,
                                              const float* __restrict__ W2,
                                              unsigned short* __restrict__ W2bf,
                                              const float* __restrict__ pos,
                                              float4* __restrict__ pos4,
                                              const float* __restrict__ pos_skip,
                                              const int* __restrict__ batch_skip,
                                              float* __restrict__ out_pos,
                                              float* __restrict__ out_batch) {
    int gid = blockIdx.x * 256 + threadIdx.x;
    int stride = gridDim.x * 256;
    for (int i = gid; i < C_H * C_IN; i += stride) W1bf[i] = f2bf(W1[i]);
    for (int i = gid; i < C_H * C_H; i += stride)  W2bf[i] = f2bf(W2[i]);
    for (int p = gid; p < NB * N_SRC; p += stride) {
        pos4[p] = make_float4(pos[p * 3 + 0], pos[p * 3 + 1], pos[p * 3 + 2], 0.f);
    }
    for (int i = gid; i < N_ROWS * 3 / 4; i += stride) {
        ((float4*)out_pos)[i] = ((const float4*)pos_skip)[i];
    }
    for (int i = gid; i < N_ROWS; i += stride) {
        out_batch[i] = (float)batch_skip[i];
    }
}

// ---------------------------------------------------------------------------
// Fused KNN + GEMM1, 512 threads (8 waves). XCD-aware: cloud = blk & 7 so a
// cloud's 128 blocks land on one XCD (x stays L2-resident per XCD).
// Scan: verified s_load_dwordx16 branchy top-3 (r12/r13 inner loop).
// MFMA1 split across all 8 waves: wave v = (wr=v&3, wc=v>>2) does rows
// [16wr,+16) x cols [64wc,+64), acc[4].
// Epilogue: if h1bf != null, store h1 as bf16 via LDS repack (coalesced);
// else fp32 to out. BN1 partials either way.
// ---------------------------------------------------------------------------
__global__ __launch_bounds__(512, 8) void k_fused1(
    const float4* __restrict__ pos4, const float* __restrict__ pos_skip,
    const float* __restrict__ x, const float* __restrict__ x_skip,
    const unsigned short* __restrict__ Wbf, const float* __restrict__ bias,
    float* __restrict__ out, unsigned short* __restrict__ h1bf,
    float* __restrict__ ps, float* __restrict__ pq) {
    __shared__ __align__(16) unsigned short Ash[64][200];  // 25600 B (overlays)
    __shared__ float sS[4][128];
    __shared__ float sQ[4][128];
    __shared__ int   midx[64][3];
    __shared__ float mw[64][3];

    float* cd = (float*)&Ash[0][0];                  // [8*64*3] floats (6144 B)
    int*   ci = (int*)((char*)&Ash[0][0] + 6144);    // [8*64*3] ints   (6144 B)

    int tid = threadIdx.x;
    int l = tid & 63;
    int v = __builtin_amdgcn_readfirstlane(tid >> 6);  // uniform wave id 0..7
    int blk = blockIdx.x;
    int cloud = blk & 7;                               // XCD-pinned cloud
    int tile  = blk >> 3;
    int r0 = cloud * N_DST + tile * 64;

    // ---------------- scan: 8 waves x 256 points ----------------
    int dst = r0 + l;
    float px = pos_skip[dst * 3 + 0];
    float py = pos_skip[dst * 3 + 1];
    float pz = pos_skip[dst * 3 + 2];

    float rr0 = 3.4e38f, rr1 = 3.4e38f, rr2 = 3.4e38f;
    int   ii0 = 0, ii1 = 0, ii2 = 0;

    const char* sp = (const char*)(pos4 + (cloud << 11) + (v << 8));
    for (int g = 0; g < 32; ++g) {           // 32 groups x 8 points
        sf16 A, B;
        asm volatile("s_load_dwordx16 %0, %2, 0x0\n\t"
                     "s_load_dwordx16 %1, %2, 0x40\n\t"
                     "s_waitcnt lgkmcnt(0)"
                     : "=s"(A), "=s"(B)
                     : "s"(sp));
        sp += 128;
        int jb = (v << 8) + g * 8;
#pragma unroll
        for (int k = 0; k < 4; ++k) {
            float dx = px - A[4 * k], dy = py - A[4 * k + 1], dz = pz - A[4 * k + 2];
            float d = fmaf(dx, dx, fmaf(dy, dy, dz * dz));
            if (d < rr2) {
                int jj = jb + k;
                bool c0 = d < rr0, c1 = d < rr1;
                ii2 = c1 ? ii1 : jj;              rr2 = c1 ? rr1 : d;
                ii1 = c1 ? (c0 ? ii0 : jj) : ii1; rr1 = c1 ? (c0 ? rr0 : d) : rr1;
                ii0 = c0 ? jj : ii0;              rr0 = c0 ? d : rr0;
            }
        }
#pragma unroll
        for (int k = 0; k < 4; ++k) {
            float dx = px - B[4 * k], dy = py - B[4 * k + 1], dz = pz - B[4 * k + 2];
            float d = fmaf(dx, dx, fmaf(dy, dy, dz * dz));
            if (d < rr2) {
                int jj = jb + 4 + k;
                bool c0 = d < rr0, c1 = d < rr1;
                ii2 = c1 ? ii1 : jj;              rr2 = c1 ? rr1 : d;
                ii1 = c1 ? (c0 ? ii0 : jj) : ii1; rr1 = c1 ? (c0 ? rr0 : d) : rr1;
                ii0 = c0 ? jj : ii0;              rr0 = c0 ? d : rr0;
            }
        }
    }
    cd[(v * 64 + l) * 3 + 0] = rr0; ci[(v * 64 + l) * 3 + 0] = ii0;
    cd[(v * 64 + l) * 3 + 1] = rr1; ci[(v * 64 + l) * 3 + 1] = ii1;
    cd[(v * 64 + l) * 3 + 2] = rr2; ci[(v * 64 + l) * 3 + 2] = ii2;
    __syncthreads();

    // ---------------- merge 24 candidates per dst ----------------
    if (tid < 64) {
        float e0 = 3.4e38f, e1 = 3.4e38f, e2 = 3.4e38f;
        int   m0 = 0, m1 = 0, m2 = 0;
#pragma unroll
        for (int s = 0; s < 8; ++s) {
#pragma unroll
            for (int t = 0; t < 3; ++t) {
                float d = cd[(s * 64 + tid) * 3 + t];
                int  jj = ci[(s * 64 + tid) * 3 + t];
                if (d < e2) {
                    bool c0 = d < e0, c1 = d < e1;
                    m2 = c1 ? m1 : jj;            e2 = c1 ? e1 : d;
                    m1 = c1 ? (c0 ? m0 : jj) : m1; e1 = c1 ? (c0 ? e0 : d) : e1;
                    m0 = c0 ? jj : m0;            e0 = c0 ? d : e0;
                }
            }
        }
        float w0 = 1.f / fmaxf(e0, 1e-16f);
        float w1 = 1.f / fmaxf(e1, 1e-16f);
        float w2 = 1.f / fmaxf(e2, 1e-16f);
        float inv = 1.f / (w0 + w1 + w2);
        midx[tid][0] = m0; midx[tid][1] = m1; midx[tid][2] = m2;
        mw[tid][0] = w0 * inv; mw[tid][1] = w1 * inv; mw[tid][2] = w2 * inv;
    }
    __syncthreads();

    // ---------------- gather: 8 waves x 8 rows -> bf16 A-tile ----------------
    const float* xb = x + (size_t)cloud * N_SRC * C_SRC;
    for (int rr = v * 8; rr < v * 8 + 8; ++rr) {
        int j0 = midx[rr][0], j1 = midx[rr][1], j2 = midx[rr][2];
        float w0 = mw[rr][0], w1 = mw[rr][1], w2 = mw[rr][2];
        const float2* x0v = (const float2*)(xb + (size_t)j0 * C_SRC);
        const float2* x1v = (const float2*)(xb + (size_t)j1 * C_SRC);
        const float2* x2v = (const float2*)(xb + (size_t)j2 * C_SRC);
        float2 a = x0v[l], b = x1v[l], c = x2v[l];
        float v0 = w0 * a.x + w1 * b.x + w2 * c.x;
        float v1 = w0 * a.y + w1 * b.y + w2 * c.y;
        ((unsigned*)&Ash[rr][0])[l] = (unsigned)f2bf(v0) | ((unsigned)f2bf(v1) << 16);
        Ash[rr][128 + l] = f2bf(x_skip[(size_t)(r0 + rr) * C_SKIP + l]);
    }
    __syncthreads();

    // ---------------- MFMA1: all 8 waves ----------------
    int wr = v & 3, wc = v >> 2;           // uniform
    int cl = l & 15, kh = l >> 4;
    f32x4 acc[4];
#pragma unroll
    for (int n = 0; n < 4; ++n) {
        float bv = bias[wc * 64 + n * 16 + cl];
        acc[n][0] = bv; acc[n][1] = bv; acc[n][2] = bv; acc[n][3] = bv;
    }
    const unsigned short* wb = Wbf + (size_t)(wc * 4) * 16 * C_IN +
                               (size_t)cl * C_IN + kh * 8;
    for (int kt = 0; kt < 6; ++kt) {
        short8 af = *(const short8*)&Ash[wr * 16 + cl][kt * 32 + kh * 8];
#pragma unroll
        for (int n = 0; n < 4; ++n) {
            short8 bf = *(const short8*)(wb + (size_t)n * 16 * C_IN + kt * 32);
            acc[n] = __builtin_amdgcn_mfma_f32_16x16x32_bf16(af, bf, acc[n], 0, 0, 0);
        }
    }

    // ---------------- lrelu + BN1 partials ----------------
    float pss[4], pqs[4];
#pragma unroll
    for (int n = 0; n < 4; ++n) {
        float s = 0.f, q = 0.f;
#pragma unroll
        for (int j = 0; j < 4; ++j) {
            float z = acc[n][j];
            z = z > 0.f ? z : SLOPE * z;
            acc[n][j] = z;
            s += z; q += z * z;
        }
        s += __shfl_xor(s, 16); s += __shfl_xor(s, 32);
        q += __shfl_xor(q, 16); q += __shfl_xor(q, 32);
        pss[n] = s; pqs[n] = q;
    }

    __syncthreads();     // all Ash MFMA reads complete before overwrite
    if (l < 16) {
#pragma unroll
        for (int n = 0; n < 4; ++n) {
            sS[wr][wc * 64 + n * 16 + l] = pss[n];
            sQ[wr][wc * 64 + n * 16 + l] = pqs[n];
        }
    }
    if (h1bf) {
        unsigned short* Az = (unsigned short*)&Ash[0][0];   // packed [64][128]
#pragma unroll
        for (int n = 0; n < 4; ++n) {
            int col = wc * 64 + n * 16 + cl;
#pragma unroll
            for (int j = 0; j < 4; ++j) {
                Az[(wr * 16 + kh * 4 + j) * 128 + col] = f2bf(acc[n][j]);
            }
        }
    } else {
#pragma unroll
        for (int n = 0; n < 4; ++n) {
            int col = wc * 64 + n * 16 + cl;
#pragma unroll
            for (int j = 0; j < 4; ++j) {
                out[(size_t)(r0 + wr * 16 + kh * 4 + j) * C_H + col] = acc[n][j];
            }
        }
    }
    __syncthreads();
    if (h1bf) {
        const uint4* Asrc = (const uint4*)&Ash[0][0];
        uint4* zdst = (uint4*)(h1bf + (size_t)r0 * C_H);
        for (int i = tid; i < 64 * C_H / 8; i += 512) zdst[i] = Asrc[i];
    }
    if (tid < 128) {
        float s = sS[0][tid] + sS[1][tid] + sS[2][tid] + sS[3][tid];
        float q = sQ[0][tid] + sQ[1][tid] + sQ[2][tid] + sQ[3][tid];
        ps[blk * C_H + tid] = s;
        pq[blk * C_H + tid] = q;
    }
}

// ---------------------------------------------------------------------------
// Per-channel reduce of block partials -> BN affine
// ---------------------------------------------------------------------------
__global__ __launch_bounds__(256) void k_reduce(const float* __restrict__ ps,
                                                const float* __restrict__ pq,
                                                const float* __restrict__ g,
                                                const float* __restrict__ be,
                                                float* __restrict__ a_out,
                                                float* __restrict__ c_out) {
    int col = blockIdx.x;
    float s = 0.f, q = 0.f;
    for (int b = threadIdx.x; b < GEMM_BLOCKS; b += 256) {
        s += ps[b * C_H + col];
        q += pq[b * C_H + col];
    }
    for (int off = 32; off; off >>= 1) {
        s += __shfl_down(s, off);
        q += __shfl_down(q, off);
    }
    __shared__ float rs[4], rq[4];
    if ((threadIdx.x & 63) == 0) { rs[threadIdx.x >> 6] = s; rq[threadIdx.x >> 6] = q; }
    __syncthreads();
    if (threadIdx.x == 0) {
        s = rs[0] + rs[1] + rs[2] + rs[3];
        q = rq[0] + rq[1] + rq[2] + rq[3];
        float mean = s / (float)N_ROWS;
        float var  = q / (float)N_ROWS - mean * mean;
        float a = g[col] * rsqrtf(var + BN_EPS);
        a_out[col] = a;
        c_out[col] = be[col] - mean * a;
    }
}

// ---------------------------------------------------------------------------
// GEMM2a: stage Ash = bf16(a1*h1 + c1) from h1bf (bf16) or h (fp32);
// z2 = Ash@W2bf^T + b2; lrelu; BN2 partials; stash lrelu(z2) bf16 IN PLACE
// over h1bf (use_z) so k_final is elementwise. Race-free: block reads only
// its own 64 rows before writing them.
// ---------------------------------------------------------------------------
__global__ __launch_bounds__(256) void k_g2a(const float* __restrict__ h,
                                             unsigned short* __restrict__ h1bf,
                                             const unsigned short* __restrict__ Wbf,
                                             const float* __restrict__ b2,
                                             const float* __restrict__ a1,
                                             const float* __restrict__ c1,
                                             float* __restrict__ ps,
                                             float* __restrict__ pq) {
    __shared__ __align__(16) unsigned short Ash[64][136];
    __shared__ float sS[4][128];
    __shared__ float sQ[4][128];

    int r0 = blockIdx.x * 64;
    int tid = threadIdx.x;
    int l = tid & 63, w = tid >> 6;

    if (h1bf) {
        const uint4* src = (const uint4*)(h1bf + (size_t)r0 * C_H);
        for (int i = tid; i < 64 * C_H / 8; i += 256) {
            uint4 vv = src[i];
            int c0 = (i * 8) & 127, r = (i * 8) >> 7;
            float4 a0 = *(const float4*)&a1[c0];
            float4 a4 = *(const float4*)&a1[c0 + 4];
            float4 c0v = *(const float4*)&c1[c0];
            float4 c4v = *(const float4*)&c1[c0 + 4];
            unsigned o0 = (unsigned)f2bf(fmaf(a0.x, bflo(vv.x), c0v.x)) |
                          ((unsigned)f2bf(fmaf(a0.y, bfhi(vv.x), c0v.y)) << 16);
            unsigned o1 = (unsigned)f2bf(fmaf(a0.z, bflo(vv.y), c0v.z)) |
                          ((unsigned)f2bf(fmaf(a0.w, bfhi(vv.y), c0v.w)) << 16);
            unsigned o2 = (unsigned)f2bf(fmaf(a4.x, bflo(vv.z), c4v.x)) |
                          ((unsigned)f2bf(fmaf(a4.y, bfhi(vv.z), c4v.y)) << 16);
            unsigned o3 = (unsigned)f2bf(fmaf(a4.z, bflo(vv.w), c4v.z)) |
                          ((unsigned)f2bf(fmaf(a4.w, bfhi(vv.w), c4v.w)) << 16);
            *(uint4*)&Ash[r][c0] = make_uint4(o0, o1, o2, o3);
        }
    } else {
        const float* src = h + (size_t)r0 * C_H;
        for (int i = tid * 4; i < 64 * C_H; i += 1024) {
            float4 vf = *(const float4*)&src[i];
            int r = i >> 7, c = i & 127;
            float4 av = *(const float4*)&a1[c];
            float4 cv = *(const float4*)&c1[c];
            unsigned lo = (unsigned)f2bf(fmaf(av.x, vf.x, cv.x)) |
                          ((unsigned)f2bf(fmaf(av.y, vf.y, cv.y)) << 16);
            unsigned hi = (unsigned)f2bf(fmaf(av.z, vf.z, cv.z)) |
                          ((unsigned)f2bf(fmaf(av.w, vf.w, cv.w)) << 16);
            *(uint2*)&Ash[r][c] = make_uint2(lo, hi);
        }
    }
    __syncthreads();

    int cl = l & 15, kh = l >> 4;
    f32x4 acc[8];
#pragma unroll
    for (int n = 0; n < 8; ++n) {
        float bv = b2[n * 16 + cl];
        acc[n][0] = bv; acc[n][1] = bv; acc[n][2] = bv; acc[n][3] = bv;
    }
    const unsigned short* wb = Wbf + (size_t)cl * C_H + kh * 8;
    for (int kt = 0; kt < 4; ++kt) {
        short8 af = *(const short8*)&Ash[w * 16 + cl][kt * 32 + kh * 8];
#pragma unroll
        for (int n = 0; n < 8; ++n) {
            short8 bf = *(const short8*)(wb + (size_t)n * 16 * C_H + kt * 32);
            acc[n] = __builtin_amdgcn_mfma_f32_16x16x32_bf16(af, bf, acc[n], 0, 0, 0);
        }
    }

    float pss[8], pqs[8];
#pragma unroll
    for (int n = 0; n < 8; ++n) {
        float s = 0.f, q = 0.f;
#pragma unroll
        for (int j = 0; j < 4; ++j) {
            float z = acc[n][j];
            z = z > 0.f ? z : SLOPE * z;
            acc[n][j] = z;                // keep lrelu'd z2
            s += z; q += z * z;
        }
        s += __shfl_xor(s, 16); s += __shfl_xor(s, 32);
        q += __shfl_xor(q, 16); q += __shfl_xor(q, 32);
        pss[n] = s; pqs[n] = q;
    }

    if (h1bf) {
        __syncthreads();                  // all Ash k-loop reads complete
        unsigned short* Az = (unsigned short*)&Ash[0][0];   // packed [64][128]
#pragma unroll
        for (int n = 0; n < 8; ++n) {
            int col = n * 16 + cl;
#pragma unroll
            for (int j = 0; j < 4; ++j) {
                Az[(w * 16 + kh * 4 + j) * 128 + col] = f2bf(acc[n][j]);
            }
        }
    }
    if (l < 16) {
#pragma unroll
        for (int n = 0; n < 8; ++n) {
            sS[w][n * 16 + l] = pss[n];
            sQ[w][n * 16 + l] = pqs[n];
        }
    }
    __syncthreads();
    if (h1bf) {
        const uint4* Asrc = (const uint4*)&Ash[0][0];
        uint4* zdst = (uint4*)(h1bf + (size_t)r0 * C_H);
        for (int i = tid; i < 64 * C_H / 8; i += 256) zdst[i] = Asrc[i];
    }
    if (tid < 128) {
        float s = sS[0][tid] + sS[1][tid] + sS[2][tid] + sS[3][tid];
        float q = sQ[0][tid] + sQ[1][tid] + sQ[2][tid] + sQ[3][tid];
        ps[blockIdx.x * C_H + tid] = s;
        pq[blockIdx.x * C_H + tid] = q;
    }
}

// ---------------------------------------------------------------------------
// Final (use_z): out_h = a2 * z2bf + c2, elementwise, fully coalesced.
// ---------------------------------------------------------------------------
__global__ __launch_bounds__(256) void k_final(const unsigned short* __restrict__ z2bf,
                                               const float* __restrict__ a2,
                                               const float* __restrict__ c2,
                                               float* __restrict__ out_h) {
    __shared__ float sa[128], sc[128];
    int tid = threadIdx.x;
    if (tid < 128) { sa[tid] = a2[tid]; sc[tid] = c2[tid]; }
    __syncthreads();

    int gid = blockIdx.x * 256 + tid;
    int stride = gridDim.x * 256;
    const uint4* zsrc = (const uint4*)z2bf;
    for (int i = gid; i < N_ROWS * C_H / 8; i += stride) {
        uint4 v = zsrc[i];
        int c0 = (i * 8) & 127;
        float4 o0, o1;
        o0.x = fmaf(sa[c0 + 0], bflo(v.x), sc[c0 + 0]);
        o0.y = fmaf(sa[c0 + 1], bfhi(v.x), sc[c0 + 1]);
        o0.z = fmaf(sa[c0 + 2], bflo(v.y), sc[c0 + 2]);
        o0.w = fmaf(sa[c0 + 3], bfhi(v.y), sc[c0 + 3]);
        o1.x = fmaf(sa[c0 + 4], bflo(v.z), sc[c0 + 4]);
        o1.y = fmaf(sa[c0 + 5], bfhi(v.z), sc[c0 + 5]);
        o1.z = fmaf(sa[c0 + 6], bflo(v.w), sc[c0 + 6]);
        o1.w = fmaf(sa[c0 + 7], bfhi(v.w), sc[c0 + 7]);
        *(float4*)&out_h[(size_t)i * 8]     = o0;
        *(float4*)&out_h[(size_t)i * 8 + 4] = o1;
    }
}

// ---------------------------------------------------------------------------
// GEMM2b (fallback, !use_z): recompute z2 from fp32 h1 in d_out, lrelu +
// BN2 affine, in-place write.
// ---------------------------------------------------------------------------
__global__ __launch_bounds__(256) void k_g2b(float* __restrict__ h,
                                             const unsigned short* __restrict__ Wbf,
                                             const float* __restrict__ b2,
                                             const float* __restrict__ a1,
                                             const float* __restrict__ c1,
                                             const float* __restrict__ a2,
                                             const float* __restrict__ c2) {
    __shared__ __align__(16) unsigned short Ash[64][136];

    int r0 = blockIdx.x * 64;
    int tid = threadIdx.x;
    int l = tid & 63, w = tid >> 6;

    const float* src = h + (size_t)r0 * C_H;
    for (int i = tid * 4; i < 64 * C_H; i += 1024) {
        float4 vf = *(const float4*)&src[i];
        int r = i >> 7, c = i & 127;
        float4 av = *(const float4*)&a1[c];
        float4 cv = *(const float4*)&c1[c];
        unsigned lo = (unsigned)f2bf(fmaf(av.x, vf.x, cv.x)) |
                      ((unsigned)f2bf(fmaf(av.y, vf.y, cv.y)) << 16);
        unsigned hi = (unsigned)f2bf(fmaf(av.z, vf.z, cv.z)) |
                      ((unsigned)f2bf(fmaf(av.w, vf.w, cv.w)) << 16);
        *(uint2*)&Ash[r][c] = make_uint2(lo, hi);
    }
    __syncthreads();

    int cl = l & 15, kh = l >> 4;
    f32x4 acc[8];
#pragma unroll
    for (int n = 0; n < 8; ++n) {
        float bv = b2[n * 16 + cl];
        acc[n][0] = bv; acc[n][1] = bv; acc[n][2] = bv; acc[n][3] = bv;
    }
    const unsigned short* wb = Wbf + (size_t)cl * C_H + kh * 8;
    for (int kt = 0; kt < 4; ++kt) {
        short8 af = *(const short8*)&Ash[w * 16 + cl][kt * 32 + kh * 8];
#pragma unroll
        for (int n = 0; n < 8; ++n) {
            short8 bf = *(const short8*)(wb + (size_t)n * 16 * C_H + kt * 32);
            acc[n] = __builtin_amdgcn_mfma_f32_16x16x32_bf16(af, bf, acc[n], 0, 0, 0);
        }
    }

#pragma unroll
    for (int n = 0; n < 8; ++n) {
        int col = n * 16 + cl;
        float av = a2[col], cv = c2[col];
#pragma unroll
        for (int j = 0; j < 4; ++j) {
            int row = r0 + w * 16 + kh * 4 + j;
            float z = acc[n][j];
            z = z > 0.f ? z : SLOPE * z;
            h[(size_t)row * C_H + col] = av * z + cv;
        }
    }
}

// ---------------------------------------------------------------------------
extern "C" void kernel_launch(void* const* d_in, const int* in_sizes, int n_in,
                              void* d_out, int out_size, void* d_ws, size_t ws_size,
                              hipStream_t stream) {
    const float* x          = (const float*)d_in[0];
    const float* pos        = (const float*)d_in[1];
    const float* x_skip     = (const float*)d_in[3];
    const float* pos_skip   = (const float*)d_in[4];
    const int*   batch_skip = (const int*)d_in[5];
    const float* W1  = (const float*)d_in[6];
    const float* b1  = (const float*)d_in[7];
    const float* g1  = (const float*)d_in[8];
    const float* be1 = (const float*)d_in[9];
    const float* W2  = (const float*)d_in[10];
    const float* b2  = (const float*)d_in[11];
    const float* g2  = (const float*)d_in[12];
    const float* be2 = (const float*)d_in[13];

    float* out_h     = (float*)d_out;
    float* out_pos   = out_h + (size_t)N_ROWS * C_H;
    float* out_batch = out_pos + (size_t)N_ROWS * 3;

    float* wsf = (float*)d_ws;
    float4* pos4         = (float4*)wsf;                         // 65536 floats
    unsigned short* W1bf = (unsigned short*)(wsf + 65536);       // 24576 us
    unsigned short* W2bf = (unsigned short*)(wsf + 77824);       // 16384 us
    float* p1s = wsf + 86016;                                    // 131072
    float* p1q = p1s + 131072;
    float* p2s = p1q + 131072;
    float* p2q = p2s + 131072;
    float* a1g = p2q + 131072;
    float* c1g = a1g + 128;
    float* a2g = c1g + 128;
    float* c2g = a2g + 128;
    unsigned short* zbuf = (unsigned short*)(c2g + 128);         // 8388608 us
    size_t ws_needed = ((size_t)610816 * 4) + (size_t)N_ROWS * C_H * 2;
    bool use_z = ws_size >= ws_needed;
    unsigned short* h1bf = use_z ? zbuf : (unsigned short*)nullptr;

    k_prep<<<256, 256, 0, stream>>>(W1, W1bf, W2, W2bf, pos, pos4,
                                    pos_skip, batch_skip, out_pos, out_batch);
    k_fused1<<<GEMM_BLOCKS, 512, 0, stream>>>(pos4, pos_skip, x, x_skip, W1bf, b1,
                                              out_h, h1bf, p1s, p1q);
    k_reduce<<<C_H, 256, 0, stream>>>(p1s, p1q, g1, be1, a1g, c1g);
    k_g2a<<<GEMM_BLOCKS, 256, 0, stream>>>(out_h, h1bf, W2bf, b2, a1g, c1g,
                                           p2s, p2q);
    k_reduce<<<C_H, 256, 0, stream>>>(p2s, p2q, g2, be2, a2g, c2g);
    if (use_z) {
        k_final<<<1024, 256, 0, stream>>>(zbuf, a2g, c2g, out_h);
    } else {
        k_g2b<<<GEMM_BLOCKS, 256, 0, stream>>>(out_h, W2bf, b2, a1g, c1g, a2g, c2g);
    }
}

// Round 15
// 111.419 us; speedup vs baseline: 1.9694x; 1.0130x over previous
//
#include <hip/hip_runtime.h>
#include <math.h>

#define NB 8
#define N_SRC 2048
#define N_DST 8192
#define C_SRC 128
#define C_SKIP 64
#define C_IN 192
#define C_H 128
#define N_ROWS (NB * N_DST)   /* 65536 */
#define BN_EPS 1e-5f
#define SLOPE 0.01f
#define GEMM_BLOCKS (N_ROWS / 64)   /* 1024 */

using short8 = __attribute__((ext_vector_type(8))) short;
using f32x4  = __attribute__((ext_vector_type(4))) float;
using sf16   = __attribute__((ext_vector_type(16))) float;

static __device__ __forceinline__ unsigned short f2bf(float f) {
    unsigned u = __builtin_bit_cast(unsigned, f);
    u = u + 0x7FFFu + ((u >> 16) & 1u);   // round-to-nearest-even
    return (unsigned short)(u >> 16);
}
static __device__ __forceinline__ float bflo(unsigned v) {
    return __builtin_bit_cast(float, (v & 0xFFFFu) << 16);
}
static __device__ __forceinline__ float bfhi(unsigned v) {
    return __builtin_bit_cast(float, v & 0xFFFF0000u);
}

// ---------------------------------------------------------------------------
// Prep: W1,W2 fp32 -> bf16; pos -> float4 array; pos/batch output copies.
// ---------------------------------------------------------------------------
__global__ __launch_bounds__(256) void k_prep(const float* __restrict__ W1,
                                              unsigned short* __restrict__ W1bf,
                                              const float* __restrict__ W2,
                                              unsigned short* __restrict__ W2bf,
                                              const float* __restrict__ pos,
                                              float4* __restrict__ pos4,
                                              const float* __restrict__ pos_skip,
                                              const int* __restrict__ batch_skip,
                                              float* __restrict__ out_pos,
                                              float* __restrict__ out_batch) {
    int gid = blockIdx.x * 256 + threadIdx.x;
    int stride = gridDim.x * 256;
    for (int i = gid; i < C_H * C_IN; i += stride) W1bf[i] = f2bf(W1[i]);
    for (int i = gid; i < C_H * C_H; i += stride)  W2bf[i] = f2bf(W2[i]);
    for (int p = gid; p < NB * N_SRC; p += stride) {
        pos4[p] = make_float4(pos[p * 3 + 0], pos[p * 3 + 1], pos[p * 3 + 2], 0.f);
    }
    for (int i = gid; i < N_ROWS * 3 / 4; i += stride) {
        ((float4*)out_pos)[i] = ((const float4*)pos_skip)[i];
    }
    for (int i = gid; i < N_ROWS; i += stride) {
        out_batch[i] = (float)batch_skip[i];
    }
}

// ---------------------------------------------------------------------------
// Fused KNN + GEMM1, 512 threads (8 waves). XCD-aware: cloud = blk & 7.
// TWO-PASS scan (s_load skeleton):
//  pass 1: distance-only top-3 via min/med3 (9 VALU/pt, branchless);
//  merge : exact (e0,e1,e2) + weights per dst;
//  pass 2: rescan (bit-identical dist2), branch d<=e2 wave-taken ~9%,
//          slot-classify -> midx.
// Then gather -> bf16 A-tile; MFMA1 on all 8 waves; lrelu; h1 bf16 (or fp32
// fallback); BN1 partials.
// ---------------------------------------------------------------------------
__global__ __launch_bounds__(512, 8) void k_fused1(
    const float4* __restrict__ pos4, const float* __restrict__ pos_skip,
    const float* __restrict__ x, const float* __restrict__ x_skip,
    const unsigned short* __restrict__ Wbf, const float* __restrict__ bias,
    float* __restrict__ out, unsigned short* __restrict__ h1bf,
    float* __restrict__ ps, float* __restrict__ pq) {
    __shared__ __align__(16) unsigned short Ash[64][200];  // 25600 B (overlays)
    __shared__ float sS[4][128];
    __shared__ float sQ[4][128];
    __shared__ int   midx[64][3];
    __shared__ float mw[64][3];

    float* cd = (float*)&Ash[0][0];                  // [8*64*3] floats (6144 B)
    float* eD = (float*)((char*)&Ash[0][0] + 6144);  // [64*3] floats (768 B)

    int tid = threadIdx.x;
    int l = tid & 63;
    int v = __builtin_amdgcn_readfirstlane(tid >> 6);  // uniform wave id 0..7
    int blk = blockIdx.x;
    int cloud = blk & 7;                               // XCD-pinned cloud
    int tile  = blk >> 3;
    int r0 = cloud * N_DST + tile * 64;

    int dst = r0 + l;
    float px = pos_skip[dst * 3 + 0];
    float py = pos_skip[dst * 3 + 1];
    float pz = pos_skip[dst * 3 + 2];

    // ---------------- pass 1: distance-only top-3 (branchless) --------------
    float d0 = 3.4e38f, d1 = 3.4e38f, d2 = 3.4e38f;
    {
        const char* sp = (const char*)(pos4 + (cloud << 11) + (v << 8));
        for (int g = 0; g < 32; ++g) {
            sf16 A, B;
            asm volatile("s_load_dwordx16 %0, %2, 0x0\n\t"
                         "s_load_dwordx16 %1, %2, 0x40\n\t"
                         "s_waitcnt lgkmcnt(0)"
                         : "=s"(A), "=s"(B)
                         : "s"(sp));
            sp += 128;
#pragma unroll
            for (int k = 0; k < 4; ++k) {
                float dx = px - A[4 * k], dy = py - A[4 * k + 1], dz = pz - A[4 * k + 2];
                float d = fmaf(dx, dx, fmaf(dy, dy, dz * dz));
                d2 = __builtin_amdgcn_fmed3f(d, d1, d2);   // old d1
                d1 = __builtin_amdgcn_fmed3f(d, d0, d1);   // old d0
                d0 = fminf(d0, d);
            }
#pragma unroll
            for (int k = 0; k < 4; ++k) {
                float dx = px - B[4 * k], dy = py - B[4 * k + 1], dz = pz - B[4 * k + 2];
                float d = fmaf(dx, dx, fmaf(dy, dy, dz * dz));
                d2 = __builtin_amdgcn_fmed3f(d, d1, d2);
                d1 = __builtin_amdgcn_fmed3f(d, d0, d1);
                d0 = fminf(d0, d);
            }
        }
    }
    cd[(v * 64 + l) * 3 + 0] = d0;
    cd[(v * 64 + l) * 3 + 1] = d1;
    cd[(v * 64 + l) * 3 + 2] = d2;
    __syncthreads();

    // ---------------- merge distance triples -> thresholds + weights --------
    if (tid < 64) {
        float e0 = 3.4e38f, e1 = 3.4e38f, e2 = 3.4e38f;
#pragma unroll
        for (int s = 0; s < 8; ++s) {
#pragma unroll
            for (int t = 0; t < 3; ++t) {
                float d = cd[(s * 64 + tid) * 3 + t];
                e2 = __builtin_amdgcn_fmed3f(d, e1, e2);
                e1 = __builtin_amdgcn_fmed3f(d, e0, e1);
                e0 = fminf(e0, d);
            }
        }
        float w0 = 1.f / fmaxf(e0, 1e-16f);
        float w1 = 1.f / fmaxf(e1, 1e-16f);
        float w2 = 1.f / fmaxf(e2, 1e-16f);
        float inv = 1.f / (w0 + w1 + w2);
        mw[tid][0] = w0 * inv; mw[tid][1] = w1 * inv; mw[tid][2] = w2 * inv;
        eD[tid * 3 + 0] = e0; eD[tid * 3 + 1] = e1; eD[tid * 3 + 2] = e2;
        midx[tid][0] = 0; midx[tid][1] = 0; midx[tid][2] = 0;
    }
    __syncthreads();

    // ---------------- pass 2: index recovery (branch ~9% wave-taken) --------
    {
        float e0r = eD[l * 3 + 0];
        float e1r = eD[l * 3 + 1];
        float e2r = eD[l * 3 + 2];
        const char* sp = (const char*)(pos4 + (cloud << 11) + (v << 8));
        for (int g = 0; g < 32; ++g) {
            sf16 A, B;
            asm volatile("s_load_dwordx16 %0, %2, 0x0\n\t"
                         "s_load_dwordx16 %1, %2, 0x40\n\t"
                         "s_waitcnt lgkmcnt(0)"
                         : "=s"(A), "=s"(B)
                         : "s"(sp));
            sp += 128;
            int jb = (v << 8) + g * 8;
#pragma unroll
            for (int k = 0; k < 4; ++k) {
                float dx = px - A[4 * k], dy = py - A[4 * k + 1], dz = pz - A[4 * k + 2];
                float d = fmaf(dx, dx, fmaf(dy, dy, dz * dz));
                if (d <= e2r) {
                    int slot = d <= e0r ? 0 : (d <= e1r ? 1 : 2);
                    midx[l][slot] = jb + k;
                }
            }
#pragma unroll
            for (int k = 0; k < 4; ++k) {
                float dx = px - B[4 * k], dy = py - B[4 * k + 1], dz = pz - B[4 * k + 2];
                float d = fmaf(dx, dx, fmaf(dy, dy, dz * dz));
                if (d <= e2r) {
                    int slot = d <= e0r ? 0 : (d <= e1r ? 1 : 2);
                    midx[l][slot] = jb + 4 + k;
                }
            }
        }
    }
    __syncthreads();

    // ---------------- gather: 8 waves x 8 rows -> bf16 A-tile ----------------
    const float* xb = x + (size_t)cloud * N_SRC * C_SRC;
    for (int rr = v * 8; rr < v * 8 + 8; ++rr) {
        int j0 = midx[rr][0], j1 = midx[rr][1], j2 = midx[rr][2];
        float w0 = mw[rr][0], w1 = mw[rr][1], w2 = mw[rr][2];
        const float2* x0v = (const float2*)(xb + (size_t)j0 * C_SRC);
        const float2* x1v = (const float2*)(xb + (size_t)j1 * C_SRC);
        const float2* x2v = (const float2*)(xb + (size_t)j2 * C_SRC);
        float2 a = x0v[l], b = x1v[l], c = x2v[l];
        float v0 = w0 * a.x + w1 * b.x + w2 * c.x;
        float v1 = w0 * a.y + w1 * b.y + w2 * c.y;
        ((unsigned*)&Ash[rr][0])[l] = (unsigned)f2bf(v0) | ((unsigned)f2bf(v1) << 16);
        Ash[rr][128 + l] = f2bf(x_skip[(size_t)(r0 + rr) * C_SKIP + l]);
    }
    __syncthreads();

    // ---------------- MFMA1: all 8 waves ----------------
    int wr = v & 3, wc = v >> 2;           // uniform
    int cl = l & 15, kh = l >> 4;
    f32x4 acc[4];
#pragma unroll
    for (int n = 0; n < 4; ++n) {
        float bv = bias[wc * 64 + n * 16 + cl];
        acc[n][0] = bv; acc[n][1] = bv; acc[n][2] = bv; acc[n][3] = bv;
    }
    const unsigned short* wb = Wbf + (size_t)(wc * 4) * 16 * C_IN +
                               (size_t)cl * C_IN + kh * 8;
    for (int kt = 0; kt < 6; ++kt) {
        short8 af = *(const short8*)&Ash[wr * 16 + cl][kt * 32 + kh * 8];
#pragma unroll
        for (int n = 0; n < 4; ++n) {
            short8 bf = *(const short8*)(wb + (size_t)n * 16 * C_IN + kt * 32);
            acc[n] = __builtin_amdgcn_mfma_f32_16x16x32_bf16(af, bf, acc[n], 0, 0, 0);
        }
    }

    // ---------------- lrelu + BN1 partials ----------------
    float pss[4], pqs[4];
#pragma unroll
    for (int n = 0; n < 4; ++n) {
        float s = 0.f, q = 0.f;
#pragma unroll
        for (int j = 0; j < 4; ++j) {
            float z = acc[n][j];
            z = z > 0.f ? z : SLOPE * z;
            acc[n][j] = z;
            s += z; q += z * z;
        }
        s += __shfl_xor(s, 16); s += __shfl_xor(s, 32);
        q += __shfl_xor(q, 16); q += __shfl_xor(q, 32);
        pss[n] = s; pqs[n] = q;
    }

    __syncthreads();     // all Ash MFMA reads complete before overwrite
    if (l < 16) {
#pragma unroll
        for (int n = 0; n < 4; ++n) {
            sS[wr][wc * 64 + n * 16 + l] = pss[n];
            sQ[wr][wc * 64 + n * 16 + l] = pqs[n];
        }
    }
    if (h1bf) {
        unsigned short* Az = (unsigned short*)&Ash[0][0];   // packed [64][128]
#pragma unroll
        for (int n = 0; n < 4; ++n) {
            int col = wc * 64 + n * 16 + cl;
#pragma unroll
            for (int j = 0; j < 4; ++j) {
                Az[(wr * 16 + kh * 4 + j) * 128 + col] = f2bf(acc[n][j]);
            }
        }
    } else {
#pragma unroll
        for (int n = 0; n < 4; ++n) {
            int col = wc * 64 + n * 16 + cl;
#pragma unroll
            for (int j = 0; j < 4; ++j) {
                out[(size_t)(r0 + wr * 16 + kh * 4 + j) * C_H + col] = acc[n][j];
            }
        }
    }
    __syncthreads();
    if (h1bf) {
        const uint4* Asrc = (const uint4*)&Ash[0][0];
        uint4* zdst = (uint4*)(h1bf + (size_t)r0 * C_H);
        for (int i = tid; i < 64 * C_H / 8; i += 512) zdst[i] = Asrc[i];
    }
    if (tid < 128) {
        float s = sS[0][tid] + sS[1][tid] + sS[2][tid] + sS[3][tid];
        float q = sQ[0][tid] + sQ[1][tid] + sQ[2][tid] + sQ[3][tid];
        ps[blk * C_H + tid] = s;
        pq[blk * C_H + tid] = q;
    }
}

// ---------------------------------------------------------------------------
// Per-channel reduce of block partials -> BN affine
// ---------------------------------------------------------------------------
__global__ __launch_bounds__(256) void k_reduce(const float* __restrict__ ps,
                                                const float* __restrict__ pq,
                                                const float* __restrict__ g,
                                                const float* __restrict__ be,
                                                float* __restrict__ a_out,
                                                float* __restrict__ c_out) {
    int col = blockIdx.x;
    float s = 0.f, q = 0.f;
    for (int b = threadIdx.x; b < GEMM_BLOCKS; b += 256) {
        s += ps[b * C_H + col];
        q += pq[b * C_H + col];
    }
    for (int off = 32; off; off >>= 1) {
        s += __shfl_down(s, off);
        q += __shfl_down(q, off);
    }
    __shared__ float rs[4], rq[4];
    if ((threadIdx.x & 63) == 0) { rs[threadIdx.x >> 6] = s; rq[threadIdx.x >> 6] = q; }
    __syncthreads();
    if (threadIdx.x == 0) {
        s = rs[0] + rs[1] + rs[2] + rs[3];
        q = rq[0] + rq[1] + rq[2] + rq[3];
        float mean = s / (float)N_ROWS;
        float var  = q / (float)N_ROWS - mean * mean;
        float a = g[col] * rsqrtf(var + BN_EPS);
        a_out[col] = a;
        c_out[col] = be[col] - mean * a;
    }
}

// ---------------------------------------------------------------------------
// GEMM2a: stage Ash = bf16(a1*h1 + c1) from h1bf (bf16) or h (fp32);
// z2 = Ash@W2bf^T + b2; lrelu; BN2 partials; stash lrelu(z2) bf16 IN PLACE
// over h1bf (use_z) so k_final is elementwise.
// ---------------------------------------------------------------------------
__global__ __launch_bounds__(256) void k_g2a(const float* __restrict__ h,
                                             unsigned short* __restrict__ h1bf,
                                             const unsigned short* __restrict__ Wbf,
                                             const float* __restrict__ b2,
                                             const float* __restrict__ a1,
                                             const float* __restrict__ c1,
                                             float* __restrict__ ps,
                                             float* __restrict__ pq) {
    __shared__ __align__(16) unsigned short Ash[64][136];
    __shared__ float sS[4][128];
    __shared__ float sQ[4][128];

    int r0 = blockIdx.x * 64;
    int tid = threadIdx.x;
    int l = tid & 63, w = tid >> 6;

    if (h1bf) {
        const uint4* src = (const uint4*)(h1bf + (size_t)r0 * C_H);
        for (int i = tid; i < 64 * C_H / 8; i += 256) {
            uint4 vv = src[i];
            int c0 = (i * 8) & 127, r = (i * 8) >> 7;
            float4 a0 = *(const float4*)&a1[c0];
            float4 a4 = *(const float4*)&a1[c0 + 4];
            float4 c0v = *(const float4*)&c1[c0];
            float4 c4v = *(const float4*)&c1[c0 + 4];
            unsigned o0 = (unsigned)f2bf(fmaf(a0.x, bflo(vv.x), c0v.x)) |
                          ((unsigned)f2bf(fmaf(a0.y, bfhi(vv.x), c0v.y)) << 16);
            unsigned o1 = (unsigned)f2bf(fmaf(a0.z, bflo(vv.y), c0v.z)) |
                          ((unsigned)f2bf(fmaf(a0.w, bfhi(vv.y), c0v.w)) << 16);
            unsigned o2 = (unsigned)f2bf(fmaf(a4.x, bflo(vv.z), c4v.x)) |
                          ((unsigned)f2bf(fmaf(a4.y, bfhi(vv.z), c4v.y)) << 16);
            unsigned o3 = (unsigned)f2bf(fmaf(a4.z, bflo(vv.w), c4v.z)) |
                          ((unsigned)f2bf(fmaf(a4.w, bfhi(vv.w), c4v.w)) << 16);
            *(uint4*)&Ash[r][c0] = make_uint4(o0, o1, o2, o3);
        }
    } else {
        const float* src = h + (size_t)r0 * C_H;
        for (int i = tid * 4; i < 64 * C_H; i += 1024) {
            float4 vf = *(const float4*)&src[i];
            int r = i >> 7, c = i & 127;
            float4 av = *(const float4*)&a1[c];
            float4 cv = *(const float4*)&c1[c];
            unsigned lo = (unsigned)f2bf(fmaf(av.x, vf.x, cv.x)) |
                          ((unsigned)f2bf(fmaf(av.y, vf.y, cv.y)) << 16);
            unsigned hi = (unsigned)f2bf(fmaf(av.z, vf.z, cv.z)) |
                          ((unsigned)f2bf(fmaf(av.w, vf.w, cv.w)) << 16);
            *(uint2*)&Ash[r][c] = make_uint2(lo, hi);
        }
    }
    __syncthreads();

    int cl = l & 15, kh = l >> 4;
    f32x4 acc[8];
#pragma unroll
    for (int n = 0; n < 8; ++n) {
        float bv = b2[n * 16 + cl];
        acc[n][0] = bv; acc[n][1] = bv; acc[n][2] = bv; acc[n][3] = bv;
    }
    const unsigned short* wb = Wbf + (size_t)cl * C_H + kh * 8;
    for (int kt = 0; kt < 4; ++kt) {
        short8 af = *(const short8*)&Ash[w * 16 + cl][kt * 32 + kh * 8];
#pragma unroll
        for (int n = 0; n < 8; ++n) {
            short8 bf = *(const short8*)(wb + (size_t)n * 16 * C_H + kt * 32);
            acc[n] = __builtin_amdgcn_mfma_f32_16x16x32_bf16(af, bf, acc[n], 0, 0, 0);
        }
    }

    float pss[8], pqs[8];
#pragma unroll
    for (int n = 0; n < 8; ++n) {
        float s = 0.f, q = 0.f;
#pragma unroll
        for (int j = 0; j < 4; ++j) {
            float z = acc[n][j];
            z = z > 0.f ? z : SLOPE * z;
            acc[n][j] = z;                // keep lrelu'd z2
            s += z; q += z * z;
        }
        s += __shfl_xor(s, 16); s += __shfl_xor(s, 32);
        q += __shfl_xor(q, 16); q += __shfl_xor(q, 32);
        pss[n] = s; pqs[n] = q;
    }

    if (h1bf) {
        __syncthreads();                  // all Ash k-loop reads complete
        unsigned short* Az = (unsigned short*)&Ash[0][0];   // packed [64][128]
#pragma unroll
        for (int n = 0; n < 8; ++n) {
            int col = n * 16 + cl;
#pragma unroll
            for (int j = 0; j < 4; ++j) {
                Az[(w * 16 + kh * 4 + j) * 128 + col] = f2bf(acc[n][j]);
            }
        }
    }
    if (l < 16) {
#pragma unroll
        for (int n = 0; n < 8; ++n) {
            sS[w][n * 16 + l] = pss[n];
            sQ[w][n * 16 + l] = pqs[n];
        }
    }
    __syncthreads();
    if (h1bf) {
        const uint4* Asrc = (const uint4*)&Ash[0][0];
        uint4* zdst = (uint4*)(h1bf + (size_t)r0 * C_H);
        for (int i = tid; i < 64 * C_H / 8; i += 256) zdst[i] = Asrc[i];
    }
    if (tid < 128) {
        float s = sS[0][tid] + sS[1][tid] + sS[2][tid] + sS[3][tid];
        float q = sQ[0][tid] + sQ[1][tid] + sQ[2][tid] + sQ[3][tid];
        ps[blockIdx.x * C_H + tid] = s;
        pq[blockIdx.x * C_H + tid] = q;
    }
}

// ---------------------------------------------------------------------------
// Final (use_z): out_h = a2 * z2bf + c2, elementwise, fully coalesced.
// ---------------------------------------------------------------------------
__global__ __launch_bounds__(256) void k_final(const unsigned short* __restrict__ z2bf,
                                               const float* __restrict__ a2,
                                               const float* __restrict__ c2,
                                               float* __restrict__ out_h) {
    __shared__ float sa[128], sc[128];
    int tid = threadIdx.x;
    if (tid < 128) { sa[tid] = a2[tid]; sc[tid] = c2[tid]; }
    __syncthreads();

    int gid = blockIdx.x * 256 + tid;
    int stride = gridDim.x * 256;
    const uint4* zsrc = (const uint4*)z2bf;
    for (int i = gid; i < N_ROWS * C_H / 8; i += stride) {
        uint4 v = zsrc[i];
        int c0 = (i * 8) & 127;
        float4 o0, o1;
        o0.x = fmaf(sa[c0 + 0], bflo(v.x), sc[c0 + 0]);
        o0.y = fmaf(sa[c0 + 1], bfhi(v.x), sc[c0 + 1]);
        o0.z = fmaf(sa[c0 + 2], bflo(v.y), sc[c0 + 2]);
        o0.w = fmaf(sa[c0 + 3], bfhi(v.y), sc[c0 + 3]);
        o1.x = fmaf(sa[c0 + 4], bflo(v.z), sc[c0 + 4]);
        o1.y = fmaf(sa[c0 + 5], bfhi(v.z), sc[c0 + 5]);
        o1.z = fmaf(sa[c0 + 6], bflo(v.w), sc[c0 + 6]);
        o1.w = fmaf(sa[c0 + 7], bfhi(v.w), sc[c0 + 7]);
        *(float4*)&out_h[(size_t)i * 8]     = o0;
        *(float4*)&out_h[(size_t)i * 8 + 4] = o1;
    }
}

// ---------------------------------------------------------------------------
// GEMM2b (fallback, !use_z): recompute z2 from fp32 h1 in d_out, lrelu +
// BN2 affine, in-place write.
// ---------------------------------------------------------------------------
__global__ __launch_bounds__(256) void k_g2b(float* __restrict__ h,
                                             const unsigned short* __restrict__ Wbf,
                                             const float* __restrict__ b2,
                                             const float* __restrict__ a1,
                                             const float* __restrict__ c1,
                                             const float* __restrict__ a2,
                                             const float* __restrict__ c2) {
    __shared__ __align__(16) unsigned short Ash[64][136];

    int r0 = blockIdx.x * 64;
    int tid = threadIdx.x;
    int l = tid & 63, w = tid >> 6;

    const float* src = h + (size_t)r0 * C_H;
    for (int i = tid * 4; i < 64 * C_H; i += 1024) {
        float4 vf = *(const float4*)&src[i];
        int r = i >> 7, c = i & 127;
        float4 av = *(const float4*)&a1[c];
        float4 cv = *(const float4*)&c1[c];
        unsigned lo = (unsigned)f2bf(fmaf(av.x, vf.x, cv.x)) |
                      ((unsigned)f2bf(fmaf(av.y, vf.y, cv.y)) << 16);
        unsigned hi = (unsigned)f2bf(fmaf(av.z, vf.z, cv.z)) |
                      ((unsigned)f2bf(fmaf(av.w, vf.w, cv.w)) << 16);
        *(uint2*)&Ash[r][c] = make_uint2(lo, hi);
    }
    __syncthreads();

    int cl = l & 15, kh = l >> 4;
    f32x4 acc[8];
#pragma unroll
    for (int n = 0; n < 8; ++n) {
        float bv = b2[n * 16 + cl];
        acc[n][0] = bv; acc[n][1] = bv; acc[n][2] = bv; acc[n][3] = bv;
    }
    const unsigned short* wb = Wbf + (size_t)cl * C_H + kh * 8;
    for (int kt = 0; kt < 4; ++kt) {
        short8 af = *(const short8*)&Ash[w * 16 + cl][kt * 32 + kh * 8];
#pragma unroll
        for (int n = 0; n < 8; ++n) {
            short8 bf = *(const short8*)(wb + (size_t)n * 16 * C_H + kt * 32);
            acc[n] = __builtin_amdgcn_mfma_f32_16x16x32_bf16(af, bf, acc[n], 0, 0, 0);
        }
    }

#pragma unroll
    for (int n = 0; n < 8; ++n) {
        int col = n * 16 + cl;
        float av = a2[col], cv = c2[col];
#pragma unroll
        for (int j = 0; j < 4; ++j) {
            int row = r0 + w * 16 + kh * 4 + j;
            float z = acc[n][j];
            z = z > 0.f ? z : SLOPE * z;
            h[(size_t)row * C_H + col] = av * z + cv;
        }
    }
}

// ---------------------------------------------------------------------------
extern "C" void kernel_launch(void* const* d_in, const int* in_sizes, int n_in,
                              void* d_out, int out_size, void* d_ws, size_t ws_size,
                              hipStream_t stream) {
    const float* x          = (const float*)d_in[0];
    const float* pos        = (const float*)d_in[1];
    const float* x_skip     = (const float*)d_in[3];
    const float* pos_skip   = (const float*)d_in[4];
    const int*   batch_skip = (const int*)d_in[5];
    const float* W1  = (const float*)d_in[6];
    const float* b1  = (const float*)d_in[7];
    const float* g1  = (const float*)d_in[8];
    const float* be1 = (const float*)d_in[9];
    const float* W2  = (const float*)d_in[10];
    const float* b2  = (const float*)d_in[11];
    const float* g2  = (const float*)d_in[12];
    const float* be2 = (const float*)d_in[13];

    float* out_h     = (float*)d_out;
    float* out_pos   = out_h + (size_t)N_ROWS * C_H;
    float* out_batch = out_pos + (size_t)N_ROWS * 3;

    float* wsf = (float*)d_ws;
    float4* pos4         = (float4*)wsf;                         // 65536 floats
    unsigned short* W1bf = (unsigned short*)(wsf + 65536);       // 24576 us
    unsigned short* W2bf = (unsigned short*)(wsf + 77824);       // 16384 us
    float* p1s = wsf + 86016;                                    // 131072
    float* p1q = p1s + 131072;
    float* p2s = p1q + 131072;
    float* p2q = p2s + 131072;
    float* a1g = p2q + 131072;
    float* c1g = a1g + 128;
    float* a2g = c1g + 128;
    float* c2g = a2g + 128;
    unsigned short* zbuf = (unsigned short*)(c2g + 128);         // 8388608 us
    size_t ws_needed = ((size_t)610816 * 4) + (size_t)N_ROWS * C_H * 2;
    bool use_z = ws_size >= ws_needed;
    unsigned short* h1bf = use_z ? zbuf : (unsigned short*)nullptr;

    k_prep<<<256, 256, 0, stream>>>(W1, W1bf, W2, W2bf, pos, pos4,
                                    pos_skip, batch_skip, out_pos, out_batch);
    k_fused1<<<GEMM_BLOCKS, 512, 0, stream>>>(pos4, pos_skip, x, x_skip, W1bf, b1,
                                              out_h, h1bf, p1s, p1q);
    k_reduce<<<C_H, 256, 0, stream>>>(p1s, p1q, g1, be1, a1g, c1g);
    k_g2a<<<GEMM_BLOCKS, 256, 0, stream>>>(out_h, h1bf, W2bf, b2, a1g, c1g,
                                           p2s, p2q);
    k_reduce<<<C_H, 256, 0, stream>>>(p2s, p2q, g2, be2, a2g, c2g);
    if (use_z) {
        k_final<<<1024, 256, 0, stream>>>(zbuf, a2g, c2g, out_h);
    } else {
        k_g2b<<<GEMM_BLOCKS, 256, 0, stream>>>(out_h, W2bf, b2, a1g, c1g, a2g, c2g);
    }
}